// Round 6
// baseline (1111.234 us; speedup 1.0000x reference)
//
#include <hip/hip_runtime.h>
#include <math.h>

#define S 4
#define G 3
#define NN 20000
#define EE 320000
#define D 64
#define SG (S*G)
#define RANGES 8
#define RNODES (NN/RANGES)   // 2500

static __device__ __forceinline__ float sigmf(float x){ return 1.0f/(1.0f + __expf(-x)); }

// float -> bf16 bits, round-nearest-even
static __device__ __forceinline__ unsigned short f2bf(float f){
    union { float f; unsigned u; } v; v.f = f;
    unsigned r = v.u + 0x7FFF + ((v.u >> 16) & 1);
    return (unsigned short)(r >> 16);
}

typedef short bf16x8 __attribute__((ext_vector_type(8)));
typedef float f32x4  __attribute__((ext_vector_type(4)));

// ---------------- CSR build: range-partitioned, LDS-atomic ----------------
// Block = (sg, dst-range of RNODES). Streams sg's edge list with int4 loads;
// counts/fills only dsts in its range. No global atomics; csr writes from one
// block stay in a ~160 KB window -> one XCD's L2 absorbs them.

__global__ __launch_bounds__(256) void count2_kernel(const int* __restrict__ ei,
                                                     int* __restrict__ deg){
    __shared__ int hist[RNODES];   // 10 KB
    int sg = blockIdx.x / RANGES, rg = blockIdx.x % RANGES;
    int lo = rg*RNODES;
    int tid = threadIdx.x;
    for (int i = tid; i < RNODES; i += 256) hist[i] = 0;
    __syncthreads();
    const int* dstp = ei + (size_t)(sg*2 + 1)*EE;
    for (int e = tid*4; e < EE; e += 1024){
        int4 d = *(const int4*)&dstp[e];
        unsigned a;
        a = (unsigned)(d.x - lo); if (a < RNODES) atomicAdd(&hist[a], 1);
        a = (unsigned)(d.y - lo); if (a < RNODES) atomicAdd(&hist[a], 1);
        a = (unsigned)(d.z - lo); if (a < RNODES) atomicAdd(&hist[a], 1);
        a = (unsigned)(d.w - lo); if (a < RNODES) atomicAdd(&hist[a], 1);
    }
    __syncthreads();
    for (int i = tid; i < RNODES; i += 256) deg[sg*NN + lo + i] = hist[i];
}

__global__ __launch_bounds__(256) void scan_kernel(const int* __restrict__ deg,
                                                   int* __restrict__ off){
    const int CH = (NN + 255)/256; // 79
    int sg = blockIdx.x, t = threadIdx.x;
    int base = sg*NN, obase = sg*(NN+1);
    int lo = t*CH, hi = min(lo+CH, NN);
    int s = 0;
    for (int i = lo; i < hi; ++i) s += deg[base+i];
    __shared__ int sums[256];
    sums[t] = s; __syncthreads();
    for (int ofs = 1; ofs < 256; ofs <<= 1){
        int v = (t >= ofs) ? sums[t-ofs] : 0;
        __syncthreads();
        sums[t] += v;
        __syncthreads();
    }
    int start = sums[t] - s;  // exclusive prefix at chunk start
    for (int i = lo; i < hi; ++i){
        off[obase+i] = start;
        start += deg[base+i];
    }
    if (lo < NN && hi == NN) off[obase+NN] = start; // == EE
}

__global__ __launch_bounds__(256) void fill2_kernel(const int* __restrict__ ei,
                                                    const int* __restrict__ off,
                                                    int* __restrict__ csr){
    __shared__ int cur[RNODES];    // 10 KB
    int sg = blockIdx.x / RANGES, rg = blockIdx.x % RANGES;
    int lo = rg*RNODES;
    int tid = threadIdx.x;
    const int* offb = off + sg*(NN+1);
    for (int i = tid; i < RNODES; i += 256) cur[i] = offb[lo + i];
    __syncthreads();
    const int* srcp = ei + (size_t)(sg*2 + 0)*EE;
    const int* dstp = ei + (size_t)(sg*2 + 1)*EE;
    int* csrb = csr + (size_t)sg*EE;
    for (int e = tid*4; e < EE; e += 1024){
        int4 d  = *(const int4*)&dstp[e];
        int4 s4 = *(const int4*)&srcp[e];
        unsigned a; int slot;
        a = (unsigned)(d.x - lo); if (a < RNODES){ slot = atomicAdd(&cur[a], 1); csrb[slot] = s4.x; }
        a = (unsigned)(d.y - lo); if (a < RNODES){ slot = atomicAdd(&cur[a], 1); csrb[slot] = s4.y; }
        a = (unsigned)(d.z - lo); if (a < RNODES){ slot = atomicAdd(&cur[a], 1); csrb[slot] = s4.z; }
        a = (unsigned)(d.w - lo); if (a < RNODES){ slot = atomicAdd(&cur[a], 1); csrb[slot] = s4.w; }
    }
}

// ---------------- SAGE layer: aggregate(mean via CSR) + GEMM + tanh ----------------
// out[sg][i][c] = tanh( mean[i][:] @ Wl[g] + in[i][:] @ Wr[g] + b[g] )

#define LDX 68    // 68%4==0 (b128-aligned rows), 68%32==4 (bank stagger)

__global__ __launch_bounds__(256) void layer_kernel(const float* __restrict__ in,
                                                    const int* __restrict__ off,
                                                    const int* __restrict__ csr,
                                                    const float* __restrict__ Wl,
                                                    const float* __restrict__ Wr,
                                                    const float* __restrict__ bias,
                                                    float* __restrict__ out){
    __shared__ float sXr[64*LDX];   // x tile, row-major [r][k]      17.4 KB
    __shared__ float sMr[64*LDX];   // mean tile, row-major [r][k]   17.4 KB
    __shared__ float sWt[16*LDX];   // W k-tile [kk][c]               4.4 KB

    int tile = blockIdx.x, sg = blockIdx.y;
    int g = sg % G;
    int tid = threadIdx.x;
    int row0 = tile*64;
    const float* inb = in + (size_t)sg*NN*D;

    // stage x tile row-major (float4 in, float4 out)
    for (int idx = tid; idx < 64*16; idx += 256){
        int r = idx >> 4, fq = idx & 15;
        int i = row0 + r;
        float4 v = {0,0,0,0};
        if (i < NN) v = *(const float4*)&inb[(size_t)i*D + fq*4];
        *(float4*)&sXr[r*LDX + fq*4] = v;
    }

    // aggregate mean: wave per 16 rows; 4 neighbor-groups x 16 lanes x float4; 4 gathers in flight
    {
        int wave = tid >> 6, lane = tid & 63;
        int grp = lane >> 4, fq = lane & 15, fb = fq*4;
        const int* offb = off + sg*(NN+1);
        const int* csrb = csr + (size_t)sg*EE;
        int i0 = row0 + wave*16;
        int ov = offb[min(i0 + lane, NN)];
        for (int r = 0; r < 16; ++r){
            int a   = __shfl(ov, r,   64);
            int b   = __shfl(ov, r+1, 64);
            int deg = b - a;
            float4 acc = {0.0f, 0.0f, 0.0f, 0.0f};
            for (int base = 0; base < deg; base += 64){
                int m = min(deg - base, 64);
                int cv = (lane < m) ? csrb[a + base + lane] : 0;
                int nit = (m + 7) >> 3;
                for (int it = 0; it < nit; it += 2){
                    int p0 = it*8 + grp;
                    int p1 = it*8 + 4 + grp;
                    int p2 = p0 + 8;
                    int p3 = p1 + 8;
                    int n0 = __shfl(cv, p0, 64);
                    int n1 = __shfl(cv, p1, 64);
                    int n2 = __shfl(cv, p2, 64);
                    int n3 = __shfl(cv, p3, 64);
                    float4 v0={0,0,0,0}, v1={0,0,0,0}, v2={0,0,0,0}, v3={0,0,0,0};
                    if (p0 < m) v0 = *(const float4*)&inb[(size_t)n0*D + fb];
                    if (p1 < m) v1 = *(const float4*)&inb[(size_t)n1*D + fb];
                    if (p2 < m) v2 = *(const float4*)&inb[(size_t)n2*D + fb];
                    if (p3 < m) v3 = *(const float4*)&inb[(size_t)n3*D + fb];
                    acc.x += (v0.x + v1.x) + (v2.x + v3.x);
                    acc.y += (v0.y + v1.y) + (v2.y + v3.y);
                    acc.z += (v0.z + v1.z) + (v2.z + v3.z);
                    acc.w += (v0.w + v1.w) + (v2.w + v3.w);
                }
            }
            acc.x += __shfl_xor(acc.x, 16, 64);
            acc.y += __shfl_xor(acc.y, 16, 64);
            acc.z += __shfl_xor(acc.z, 16, 64);
            acc.w += __shfl_xor(acc.w, 16, 64);
            acc.x += __shfl_xor(acc.x, 32, 64);
            acc.y += __shfl_xor(acc.y, 32, 64);
            acc.z += __shfl_xor(acc.z, 32, 64);
            acc.w += __shfl_xor(acc.w, 32, 64);
            float inv = (deg > 0) ? (1.0f/(float)deg) : 0.0f;
            if (grp == 0){
                float4 mres;
                mres.x = acc.x*inv; mres.y = acc.y*inv; mres.z = acc.z*inv; mres.w = acc.w*inv;
                *(float4*)&sMr[(wave*16 + r)*LDX + fb] = mres;
            }
        }
    }

    int tx = tid & 15, ty = tid >> 4;
    int c0 = tx*4, r0 = ty*4;
    float acc[4][4];
    #pragma unroll
    for (int i = 0; i < 4; ++i)
        #pragma unroll
        for (int j = 0; j < 4; ++j) acc[i][j] = 0.0f;

    const float* Wlg = Wl + (size_t)g*64*64;
    const float* Wrg = Wr + (size_t)g*64*64;

    #pragma unroll 1
    for (int pass = 0; pass < 2; ++pass){
        const float* Wsrc = (pass == 0) ? Wlg : Wrg;
        #pragma unroll 1
        for (int kt = 0; kt < 4; ++kt){
            __syncthreads();   // first one doubles as post-aggregation/staging barrier
            {   // stage sWt: 16 k-rows x 64 cols, one float4 per thread
                int kk = tid >> 4, cc = (tid & 15)*4;
                *(float4*)&sWt[kk*LDX + cc] = *(const float4*)&Wsrc[(kt*16 + kk)*64 + cc];
            }
            __syncthreads();
            #pragma unroll
            for (int k4 = 0; k4 < 4; ++k4){
                float a_[4][4];
                #pragma unroll
                for (int i = 0; i < 4; ++i){
                    const float* A = (pass == 0) ? &sMr[(r0+i)*LDX + kt*16 + k4*4]
                                                 : &sXr[(r0+i)*LDX + kt*16 + k4*4];
                    float4 t4 = *(const float4*)A;
                    a_[i][0]=t4.x; a_[i][1]=t4.y; a_[i][2]=t4.z; a_[i][3]=t4.w;
                }
                #pragma unroll
                for (int kk = 0; kk < 4; ++kk){
                    float4 w4 = *(const float4*)&sWt[(k4*4 + kk)*LDX + c0];
                    float w[4] = {w4.x, w4.y, w4.z, w4.w};
                    #pragma unroll
                    for (int i = 0; i < 4; ++i)
                        #pragma unroll
                        for (int j = 0; j < 4; ++j)
                            acc[i][j] = fmaf(a_[i][kk], w[j], acc[i][j]);
                }
            }
        }
    }

    float4 b4 = *(const float4*)&bias[g*64 + c0];
    float bv[4] = {b4.x, b4.y, b4.z, b4.w};
    float* outb = out + (size_t)sg*NN*D;
    #pragma unroll
    for (int i = 0; i < 4; ++i){
        int r = row0 + r0 + i;
        if (r < NN){
            float4 o;
            o.x = tanhf(acc[i][0] + bv[0]);
            o.y = tanhf(acc[i][1] + bv[1]);
            o.z = tanhf(acc[i][2] + bv[2]);
            o.w = tanhf(acc[i][3] + bv[3]);
            *(float4*)&outb[(size_t)r*D + c0] = o;
        }
    }
}

// ---------------- LSTM weight prep: Wt[col][k] bf16 (k = x||h), bc = bih+bhh ----------------

__global__ __launch_bounds__(256) void wprep_kernel(const float* __restrict__ Wih,
                                                    const float* __restrict__ Whh,
                                                    const float* __restrict__ bih,
                                                    const float* __restrict__ bhh,
                                                    unsigned short* __restrict__ Wt,
                                                    float* __restrict__ bc){
    int idx = blockIdx.x*256 + threadIdx.x;
    if (idx < 256*128){
        int col = idx >> 7, k = idx & 127;
        float v = (k < 64) ? Wih[col*64 + k] : Whh[col*64 + (k - 64)];
        Wt[idx] = f2bf(v);
    }
    if (idx < 256) bc[idx] = bih[idx] + bhh[idx];
}

// ---------------- LSTM: 3 steps fused, MFMA bf16 gate GEMM ----------------
// batch b = s*NN + n ; x_t[b] = h2[s][g=t][n][:]
// A (x||h) bf16 in LDS [row][k]; B = Wt[col][k] bf16 from global (L1/L2-hot).
// Wave w -> rows 16w..16w+15, 16 col-tiles of 16. C/D: col=lane&15, row=quad*4+reg.

#define LDA 136   // ushort pitch; 272 B rows, 16 B-aligned

__global__ __launch_bounds__(256) void lstm_kernel(const float* __restrict__ h2,
                                                   const unsigned short* __restrict__ Wt,
                                                   const float* __restrict__ bc,
                                                   float* __restrict__ out){
    __shared__ unsigned short sA[64*LDA];  // 17.4 KB: k<64 x_t, k>=64 h_{t-1}
    __shared__ float sO[64*68];            // 17.4 KB: fp32 output staging
    int tid = threadIdx.x;
    int b0 = blockIdx.x * 64;
    int wave = tid >> 6, lane = tid & 63;
    int n0 = lane & 15, q = lane >> 4;
    int rbase = wave*16;

    // bias for this lane's 16 (T, j = n0+16m) gate columns
    float bb[4][4];
    #pragma unroll
    for (int T = 0; T < 4; ++T)
        #pragma unroll
        for (int m = 0; m < 4; ++m)
            bb[T][m] = bc[T*64 + n0 + 16*m];

    float c[4][4];  // [reg(row)][m(j)]
    #pragma unroll
    for (int i = 0; i < 4; ++i)
        #pragma unroll
        for (int m = 0; m < 4; ++m) c[i][m] = 0.0f;

    for (int t = 0; t < G; ++t){
        // stage x_t as bf16 into sA[r][0..63]
        for (int idx = tid; idx < 64*16; idx += 256){
            int r = idx >> 4, fq = idx & 15;
            int b = b0 + r;
            int s = b / NN, n = b - s*NN;
            float4 v = *(const float4*)&h2[((size_t)(s*G + t)*NN + n)*D + fq*4];
            union { unsigned short u[4]; double d; } pk;
            pk.u[0] = f2bf(v.x); pk.u[1] = f2bf(v.y);
            pk.u[2] = f2bf(v.z); pk.u[3] = f2bf(v.w);
            *(double*)&sA[r*LDA + fq*4] = pk.d;   // 8 B aligned store
        }
        __syncthreads();

        int nkc = (t == 0) ? 2 : 4;   // h_0 == 0: skip h-half k-chunks
        f32x4 accv[16];
        #pragma unroll
        for (int ct = 0; ct < 16; ++ct) accv[ct] = (f32x4){0.f,0.f,0.f,0.f};

        #pragma unroll 1
        for (int kc = 0; kc < nkc; ++kc){
            bf16x8 af = *(const bf16x8*)&sA[(rbase + n0)*LDA + kc*32 + q*8];
            #pragma unroll
            for (int ct = 0; ct < 16; ++ct){
                bf16x8 bf = *(const bf16x8*)&Wt[(ct*16 + n0)*128 + kc*32 + q*8];
                accv[ct] = __builtin_amdgcn_mfma_f32_16x16x32_bf16(af, bf, accv[ct], 0, 0, 0);
            }
        }
        __syncthreads();  // all waves done reading sA before h overwrite

        // elementwise: lane owns rows rbase+q*4+reg, cols j = n0+16m (all 4 gates local)
        #pragma unroll
        for (int reg = 0; reg < 4; ++reg){
            int r = rbase + q*4 + reg;
            #pragma unroll
            for (int m = 0; m < 4; ++m){
                float ig = sigmf(accv[0*4 + m][reg] + bb[0][m]);
                float fg = sigmf(accv[1*4 + m][reg] + bb[1][m]);
                float gg = tanhf(accv[2*4 + m][reg] + bb[2][m]);
                float og = sigmf(accv[3*4 + m][reg] + bb[3][m]);
                float cn = fg*c[reg][m] + ig*gg;
                c[reg][m] = cn;
                float hv = og * tanhf(cn);
                if (t < G-1) sA[r*LDA + 64 + n0 + 16*m] = f2bf(hv);  // h for next step
                else         sO[r*68 + n0 + 16*m] = hv;
            }
        }
        // h/sO writes become visible at the next loop's post-staging barrier /
        // the epilogue barrier below.
    }

    __syncthreads();
    for (int idx = tid; idx < 64*16; idx += 256){
        int r = idx >> 4, fq = idx & 15;
        float4 v = *(const float4*)&sO[r*68 + fq*4];
        *(float4*)&out[(size_t)(b0 + r)*D + fq*4] = v;
    }
}

// ---------------- host ----------------

extern "C" void kernel_launch(void* const* d_in, const int* in_sizes, int n_in,
                              void* d_out, int out_size, void* d_ws, size_t ws_size,
                              hipStream_t stream) {
    const float* x   = (const float*)d_in[0];
    const int*   ei  = (const int*)  d_in[1];
    const float* W1l = (const float*)d_in[2];
    const float* W1r = (const float*)d_in[3];
    const float* b1  = (const float*)d_in[4];
    const float* W2l = (const float*)d_in[5];
    const float* W2r = (const float*)d_in[6];
    const float* b2  = (const float*)d_in[7];
    const float* Wih = (const float*)d_in[8];
    const float* Whh = (const float*)d_in[9];
    const float* bih = (const float*)d_in[10];
    const float* bhh = (const float*)d_in[11];
    float* out = (float*)d_out;

    char* ws = (char*)d_ws;
    size_t cur = 0;
    auto alloc = [&](size_t bytes)->void*{
        cur = (cur + 255) & ~(size_t)255;
        void* p = ws + cur; cur += bytes; return p;
    };
    int*   deg    = (int*)  alloc((size_t)SG*NN*4);
    int*   off    = (int*)  alloc((size_t)SG*(NN+1)*4);
    int*   csr    = (int*)  alloc((size_t)SG*EE*4);
    float* h1     = (float*)alloc((size_t)SG*NN*D*4);
    float* h2     = (float*)alloc((size_t)SG*NN*D*4);
    unsigned short* Wt = (unsigned short*)alloc((size_t)256*128*2);
    float* bc     = (float*)alloc((size_t)256*4);
    (void)ws_size; (void)in_sizes; (void)n_in; (void)out_size;

    count2_kernel<<<SG*RANGES, 256, 0, stream>>>(ei, deg);
    scan_kernel  <<<SG, 256, 0, stream>>>(deg, off);
    fill2_kernel <<<SG*RANGES, 256, 0, stream>>>(ei, off, csr);

    dim3 lgrid((NN + 63)/64, SG);
    layer_kernel<<<lgrid, 256, 0, stream>>>(x,  off, csr, W1l, W1r, b1, h1);
    layer_kernel<<<lgrid, 256, 0, stream>>>(h1, off, csr, W2l, W2r, b2, h2);

    wprep_kernel<<<128, 256, 0, stream>>>(Wih, Whh, bih, bhh, Wt, bc);
    lstm_kernel <<<(S*NN)/64, 256, 0, stream>>>(h2, Wt, bc, out);
}

// Round 7
// 648.384 us; speedup vs baseline: 1.7139x; 1.7139x over previous
//
#include <hip/hip_runtime.h>
#include <math.h>

#define S 4
#define G 3
#define NN 20000
#define EE 320000
#define D 64
#define SG (S*G)

#define RGS 32           // dst-ranges per graph
#define RNODES2 625      // NN / RGS
#define BCAP 12000       // bucket capacity per (sg,range); mean 10000, +20 sigma
#define CHUNKA 25        // edge chunks per sg in binA; 320000/25 = 12800 edges/block

static __device__ __forceinline__ float sigmf(float x){ return 1.0f/(1.0f + __expf(-x)); }

// float -> bf16 bits, round-nearest-even
static __device__ __forceinline__ unsigned short f2bf(float f){
    union { float f; unsigned u; } v; v.f = f;
    unsigned r = v.u + 0x7FFF + ((v.u >> 16) & 1);
    return (unsigned short)(r >> 16);
}

typedef short bf16x8 __attribute__((ext_vector_type(8)));
typedef float f32x4  __attribute__((ext_vector_type(4)));

// ---------------- Phase A: bin edges into 32 dst-range buckets, packed (dstLoc<<15)|src ----------------
// Block = (chunk, sg); streams 12800 edges once; per-tile block reservation via one
// global atomicAdd per (range,tile). Writes are near-contiguous runs -> dense lines.

__global__ __launch_bounds__(256) void binA_kernel(const int* __restrict__ ei,
                                                   int* __restrict__ bcur,
                                                   int* __restrict__ bkt){
    __shared__ int wcnt[4*RGS];   // per-wave per-range counts
    __shared__ int wb[4*RGS];     // per-wave per-range write bases
    int chunk = blockIdx.x, sg = blockIdx.y;
    int tid = threadIdx.x, w = tid >> 6;
    const int* srcp = ei + (size_t)(sg*2 + 0)*EE;
    const int* dstp = ei + (size_t)(sg*2 + 1)*EE;
    int start = chunk*12800, end = start + 12800;

    for (int it = 0; it < 13; ++it){
        if (tid < 4*RGS) wcnt[tid] = 0;
        __syncthreads();
        int e = start + it*1024 + tid*4;
        bool valid = e < end;
        int d_[4], s_[4], r_[4], dl_[4], rk_[4];
        if (valid){
            int4 d4 = *(const int4*)&dstp[e];
            int4 s4 = *(const int4*)&srcp[e];
            d_[0]=d4.x; d_[1]=d4.y; d_[2]=d4.z; d_[3]=d4.w;
            s_[0]=s4.x; s_[1]=s4.y; s_[2]=s4.z; s_[3]=s4.w;
            #pragma unroll
            for (int j = 0; j < 4; ++j){
                int r = d_[j] / RNODES2;
                r_[j]  = r;
                dl_[j] = d_[j] - r*RNODES2;
                rk_[j] = atomicAdd(&wcnt[w*RGS + r], 1);
            }
        }
        __syncthreads();
        if (tid < RGS){
            int c0 = wcnt[0*RGS+tid], c1 = wcnt[1*RGS+tid];
            int c2 = wcnt[2*RGS+tid], c3 = wcnt[3*RGS+tid];
            int tot = c0+c1+c2+c3;
            int gb = 0;
            if (tot > 0) gb = atomicAdd(&bcur[sg*RGS + tid], tot);
            wb[0*RGS+tid] = gb;
            wb[1*RGS+tid] = gb + c0;
            wb[2*RGS+tid] = gb + c0 + c1;
            wb[3*RGS+tid] = gb + c0 + c1 + c2;
        }
        __syncthreads();
        if (valid){
            #pragma unroll
            for (int j = 0; j < 4; ++j){
                int pos = wb[w*RGS + r_[j]] + rk_[j];
                if (pos < BCAP)
                    bkt[(size_t)(sg*RGS + r_[j])*BCAP + pos] = (dl_[j] << 15) | s_[j];
            }
        }
    }
}

// ---------------- Phase B: per (sg,range): hist -> scan -> CSR segment in LDS -> in-place dump ----------------
// Emits absolute off[] and deg[]; csr lives in the bucket array (overwritten in place).

__global__ __launch_bounds__(256) void buildB_kernel(int* __restrict__ bkt,
                                                     const int* __restrict__ bcur,
                                                     int* __restrict__ off2,
                                                     int* __restrict__ deg2){
    __shared__ int hist[RNODES2];
    __shared__ int pref[RNODES2];
    __shared__ int seg[BCAP];     // 48 KB
    __shared__ int sums[256];
    int sg = blockIdx.x / RGS, rg = blockIdx.x % RGS;
    int tid = threadIdx.x;
    int cnt = bcur[sg*RGS + rg];
    if (cnt > BCAP) cnt = BCAP;
    size_t base = (size_t)(sg*RGS + rg)*BCAP;

    for (int i = tid; i < RNODES2; i += 256) hist[i] = 0;
    __syncthreads();
    for (int j = tid; j < cnt; j += 256)
        atomicAdd(&hist[bkt[base + j] >> 15], 1);
    __syncthreads();

    // block scan over 625 entries, 3 per thread
    int lo = tid*3, hi = min(lo+3, RNODES2);
    int s = 0;
    for (int i = lo; i < hi; ++i) s += hist[i];
    sums[tid] = s; __syncthreads();
    for (int ofs = 1; ofs < 256; ofs <<= 1){
        int v = (tid >= ofs) ? sums[tid-ofs] : 0;
        __syncthreads();
        sums[tid] += v;
        __syncthreads();
    }
    int run = sums[tid] - s;   // exclusive prefix at chunk start
    int gnode = sg*NN + rg*RNODES2;
    for (int i = lo; i < hi; ++i){
        pref[i] = run;
        off2[gnode + i] = (int)base + run;
        deg2[gnode + i] = hist[i];
        run += hist[i];
    }
    __syncthreads();

    // place into LDS segment
    for (int j = tid; j < cnt; j += 256){
        int p = bkt[base + j];
        int slot = atomicAdd(&pref[p >> 15], 1);
        seg[slot] = p & 0x7FFF;
    }
    __syncthreads();

    // coalesced in-place dump (bucket region becomes the CSR segment)
    for (int j = tid; j < cnt; j += 256) bkt[base + j] = seg[j];
}

// ---------------- SAGE layer: aggregate(mean via CSR) + GEMM + tanh ----------------

#define LDX 68

__global__ __launch_bounds__(256) void layer_kernel(const float* __restrict__ in,
                                                    const int* __restrict__ off2,
                                                    const int* __restrict__ deg2,
                                                    const int* __restrict__ csr,
                                                    const float* __restrict__ Wl,
                                                    const float* __restrict__ Wr,
                                                    const float* __restrict__ bias,
                                                    float* __restrict__ out){
    __shared__ float sXr[64*LDX];
    __shared__ float sMr[64*LDX];
    __shared__ float sWt[16*LDX];

    int tile = blockIdx.x, sg = blockIdx.y;
    int g = sg % G;
    int tid = threadIdx.x;
    int row0 = tile*64;
    const float* inb = in + (size_t)sg*NN*D;

    for (int idx = tid; idx < 64*16; idx += 256){
        int r = idx >> 4, fq = idx & 15;
        int i = row0 + r;
        float4 v = {0,0,0,0};
        if (i < NN) v = *(const float4*)&inb[(size_t)i*D + fq*4];
        *(float4*)&sXr[r*LDX + fq*4] = v;
    }

    {
        int wave = tid >> 6, lane = tid & 63;
        int grp = lane >> 4, fq = lane & 15, fb = fq*4;
        const int* offb = off2 + sg*NN;
        const int* degb = deg2 + sg*NN;
        int i0 = row0 + wave*16;
        int ii = min(i0 + (lane & 15), NN-1);
        int val = (lane < 32) ? ((lane < 16) ? offb[ii] : degb[ii]) : 0;
        for (int r = 0; r < 16; ++r){
            int i  = i0 + r;
            int a  = __shfl(val, r,      64);
            int dg = __shfl(val, 16 + r, 64);
            if (i >= NN) dg = 0;
            float4 acc = {0.0f, 0.0f, 0.0f, 0.0f};
            for (int base = 0; base < dg; base += 64){
                int m = min(dg - base, 64);
                int cv = (lane < m) ? csr[a + base + lane] : 0;
                int nit = (m + 7) >> 3;
                for (int it = 0; it < nit; it += 2){
                    int p0 = it*8 + grp;
                    int p1 = it*8 + 4 + grp;
                    int p2 = p0 + 8;
                    int p3 = p1 + 8;
                    int n0 = __shfl(cv, p0, 64);
                    int n1 = __shfl(cv, p1, 64);
                    int n2 = __shfl(cv, p2, 64);
                    int n3 = __shfl(cv, p3, 64);
                    float4 v0={0,0,0,0}, v1={0,0,0,0}, v2={0,0,0,0}, v3={0,0,0,0};
                    if (p0 < m) v0 = *(const float4*)&inb[(size_t)n0*D + fb];
                    if (p1 < m) v1 = *(const float4*)&inb[(size_t)n1*D + fb];
                    if (p2 < m) v2 = *(const float4*)&inb[(size_t)n2*D + fb];
                    if (p3 < m) v3 = *(const float4*)&inb[(size_t)n3*D + fb];
                    acc.x += (v0.x + v1.x) + (v2.x + v3.x);
                    acc.y += (v0.y + v1.y) + (v2.y + v3.y);
                    acc.z += (v0.z + v1.z) + (v2.z + v3.z);
                    acc.w += (v0.w + v1.w) + (v2.w + v3.w);
                }
            }
            acc.x += __shfl_xor(acc.x, 16, 64);
            acc.y += __shfl_xor(acc.y, 16, 64);
            acc.z += __shfl_xor(acc.z, 16, 64);
            acc.w += __shfl_xor(acc.w, 16, 64);
            acc.x += __shfl_xor(acc.x, 32, 64);
            acc.y += __shfl_xor(acc.y, 32, 64);
            acc.z += __shfl_xor(acc.z, 32, 64);
            acc.w += __shfl_xor(acc.w, 32, 64);
            float inv = (dg > 0) ? (1.0f/(float)dg) : 0.0f;
            if (grp == 0){
                float4 mres;
                mres.x = acc.x*inv; mres.y = acc.y*inv; mres.z = acc.z*inv; mres.w = acc.w*inv;
                *(float4*)&sMr[(wave*16 + r)*LDX + fb] = mres;
            }
        }
    }

    int tx = tid & 15, ty = tid >> 4;
    int c0 = tx*4, r0 = ty*4;
    float acc[4][4];
    #pragma unroll
    for (int i = 0; i < 4; ++i)
        #pragma unroll
        for (int j = 0; j < 4; ++j) acc[i][j] = 0.0f;

    const float* Wlg = Wl + (size_t)g*64*64;
    const float* Wrg = Wr + (size_t)g*64*64;

    #pragma unroll 1
    for (int pass = 0; pass < 2; ++pass){
        const float* Wsrc = (pass == 0) ? Wlg : Wrg;
        #pragma unroll 1
        for (int kt = 0; kt < 4; ++kt){
            __syncthreads();
            {
                int kk = tid >> 4, cc = (tid & 15)*4;
                *(float4*)&sWt[kk*LDX + cc] = *(const float4*)&Wsrc[(kt*16 + kk)*64 + cc];
            }
            __syncthreads();
            #pragma unroll
            for (int k4 = 0; k4 < 4; ++k4){
                float a_[4][4];
                #pragma unroll
                for (int i = 0; i < 4; ++i){
                    const float* A = (pass == 0) ? &sMr[(r0+i)*LDX + kt*16 + k4*4]
                                                 : &sXr[(r0+i)*LDX + kt*16 + k4*4];
                    float4 t4 = *(const float4*)A;
                    a_[i][0]=t4.x; a_[i][1]=t4.y; a_[i][2]=t4.z; a_[i][3]=t4.w;
                }
                #pragma unroll
                for (int kk = 0; kk < 4; ++kk){
                    float4 w4 = *(const float4*)&sWt[(k4*4 + kk)*LDX + c0];
                    float w[4] = {w4.x, w4.y, w4.z, w4.w};
                    #pragma unroll
                    for (int i = 0; i < 4; ++i)
                        #pragma unroll
                        for (int j = 0; j < 4; ++j)
                            acc[i][j] = fmaf(a_[i][kk], w[j], acc[i][j]);
                }
            }
        }
    }

    float4 b4 = *(const float4*)&bias[g*64 + c0];
    float bv[4] = {b4.x, b4.y, b4.z, b4.w};
    float* outb = out + (size_t)sg*NN*D;
    #pragma unroll
    for (int i = 0; i < 4; ++i){
        int r = row0 + r0 + i;
        if (r < NN){
            float4 o;
            o.x = tanhf(acc[i][0] + bv[0]);
            o.y = tanhf(acc[i][1] + bv[1]);
            o.z = tanhf(acc[i][2] + bv[2]);
            o.w = tanhf(acc[i][3] + bv[3]);
            *(float4*)&outb[(size_t)r*D + c0] = o;
        }
    }
}

// ---------------- LSTM weight prep ----------------

__global__ __launch_bounds__(256) void wprep_kernel(const float* __restrict__ Wih,
                                                    const float* __restrict__ Whh,
                                                    const float* __restrict__ bih,
                                                    const float* __restrict__ bhh,
                                                    unsigned short* __restrict__ Wt,
                                                    float* __restrict__ bc){
    int idx = blockIdx.x*256 + threadIdx.x;
    if (idx < 256*128){
        int col = idx >> 7, k = idx & 127;
        float v = (k < 64) ? Wih[col*64 + k] : Whh[col*64 + (k - 64)];
        Wt[idx] = f2bf(v);
    }
    if (idx < 256) bc[idx] = bih[idx] + bhh[idx];
}

// ---------------- LSTM: 3 steps fused, MFMA bf16 gate GEMM ----------------

#define LDA 136

__global__ __launch_bounds__(256) void lstm_kernel(const float* __restrict__ h2,
                                                   const unsigned short* __restrict__ Wt,
                                                   const float* __restrict__ bc,
                                                   float* __restrict__ out){
    __shared__ unsigned short sA[64*LDA];
    __shared__ float sO[64*68];
    int tid = threadIdx.x;
    int b0 = blockIdx.x * 64;
    int wave = tid >> 6, lane = tid & 63;
    int n0 = lane & 15, q = lane >> 4;
    int rbase = wave*16;

    float bb[4][4];
    #pragma unroll
    for (int T = 0; T < 4; ++T)
        #pragma unroll
        for (int m = 0; m < 4; ++m)
            bb[T][m] = bc[T*64 + n0 + 16*m];

    float c[4][4];
    #pragma unroll
    for (int i = 0; i < 4; ++i)
        #pragma unroll
        for (int m = 0; m < 4; ++m) c[i][m] = 0.0f;

    for (int t = 0; t < G; ++t){
        for (int idx = tid; idx < 64*16; idx += 256){
            int r = idx >> 4, fq = idx & 15;
            int b = b0 + r;
            int s = b / NN, n = b - s*NN;
            float4 v = *(const float4*)&h2[((size_t)(s*G + t)*NN + n)*D + fq*4];
            union { unsigned short u[4]; double d; } pk;
            pk.u[0] = f2bf(v.x); pk.u[1] = f2bf(v.y);
            pk.u[2] = f2bf(v.z); pk.u[3] = f2bf(v.w);
            *(double*)&sA[r*LDA + fq*4] = pk.d;
        }
        __syncthreads();

        int nkc = (t == 0) ? 2 : 4;
        f32x4 accv[16];
        #pragma unroll
        for (int ct = 0; ct < 16; ++ct) accv[ct] = (f32x4){0.f,0.f,0.f,0.f};

        #pragma unroll 1
        for (int kc = 0; kc < nkc; ++kc){
            bf16x8 af = *(const bf16x8*)&sA[(rbase + n0)*LDA + kc*32 + q*8];
            #pragma unroll
            for (int ct = 0; ct < 16; ++ct){
                bf16x8 bf = *(const bf16x8*)&Wt[(ct*16 + n0)*128 + kc*32 + q*8];
                accv[ct] = __builtin_amdgcn_mfma_f32_16x16x32_bf16(af, bf, accv[ct], 0, 0, 0);
            }
        }
        __syncthreads();

        #pragma unroll
        for (int reg = 0; reg < 4; ++reg){
            int r = rbase + q*4 + reg;
            #pragma unroll
            for (int m = 0; m < 4; ++m){
                float ig = sigmf(accv[0*4 + m][reg] + bb[0][m]);
                float fg = sigmf(accv[1*4 + m][reg] + bb[1][m]);
                float gg = tanhf(accv[2*4 + m][reg] + bb[2][m]);
                float og = sigmf(accv[3*4 + m][reg] + bb[3][m]);
                float cn = fg*c[reg][m] + ig*gg;
                c[reg][m] = cn;
                float hv = og * tanhf(cn);
                if (t < G-1) sA[r*LDA + 64 + n0 + 16*m] = f2bf(hv);
                else         sO[r*68 + n0 + 16*m] = hv;
            }
        }
    }

    __syncthreads();
    for (int idx = tid; idx < 64*16; idx += 256){
        int r = idx >> 4, fq = idx & 15;
        float4 v = *(const float4*)&sO[r*68 + fq*4];
        *(float4*)&out[(size_t)(b0 + r)*D + fq*4] = v;
    }
}

// ---------------- host ----------------

extern "C" void kernel_launch(void* const* d_in, const int* in_sizes, int n_in,
                              void* d_out, int out_size, void* d_ws, size_t ws_size,
                              hipStream_t stream) {
    const float* x   = (const float*)d_in[0];
    const int*   ei  = (const int*)  d_in[1];
    const float* W1l = (const float*)d_in[2];
    const float* W1r = (const float*)d_in[3];
    const float* b1  = (const float*)d_in[4];
    const float* W2l = (const float*)d_in[5];
    const float* W2r = (const float*)d_in[6];
    const float* b2  = (const float*)d_in[7];
    const float* Wih = (const float*)d_in[8];
    const float* Whh = (const float*)d_in[9];
    const float* bih = (const float*)d_in[10];
    const float* bhh = (const float*)d_in[11];
    float* out = (float*)d_out;

    char* ws = (char*)d_ws;
    size_t cur = 0;
    auto alloc = [&](size_t bytes)->void*{
        cur = (cur + 255) & ~(size_t)255;
        void* p = ws + cur; cur += bytes; return p;
    };
    int*   bkt  = (int*)alloc((size_t)SG*RGS*BCAP*4);   // buckets, then CSR in place (18.4 MB)
    int*   bcur = (int*)alloc((size_t)SG*RGS*4);
    int*   off2 = (int*)alloc((size_t)SG*NN*4);
    int*   deg2 = (int*)alloc((size_t)SG*NN*4);
    float* h1   = (float*)alloc((size_t)SG*NN*D*4);
    float* h2   = (float*)alloc((size_t)SG*NN*D*4);
    unsigned short* Wt = (unsigned short*)alloc((size_t)256*128*2);
    float* bc   = (float*)alloc((size_t)256*4);
    (void)ws_size; (void)in_sizes; (void)n_in; (void)out_size;

    (void)hipMemsetAsync(bcur, 0, (size_t)SG*RGS*4, stream);

    binA_kernel  <<<dim3(CHUNKA, SG), 256, 0, stream>>>(ei, bcur, bkt);
    buildB_kernel<<<SG*RGS, 256, 0, stream>>>(bkt, bcur, off2, deg2);

    dim3 lgrid((NN + 63)/64, SG);
    layer_kernel<<<lgrid, 256, 0, stream>>>(x,  off2, deg2, bkt, W1l, W1r, b1, h1);
    layer_kernel<<<lgrid, 256, 0, stream>>>(h1, off2, deg2, bkt, W2l, W2r, b2, h2);

    wprep_kernel<<<128, 256, 0, stream>>>(Wih, Whh, bih, bhh, Wt, bc);
    lstm_kernel <<<(S*NN)/64, 256, 0, stream>>>(h2, Wt, bc, out);
}

// Round 8
// 525.760 us; speedup vs baseline: 2.1136x; 1.2332x over previous
//
#include <hip/hip_runtime.h>
#include <math.h>

#define S 4
#define G 3
#define NN 20000
#define EE 320000
#define D 64
#define SG (S*G)

#define RGS 32           // dst-ranges per graph
#define RNODES2 625      // NN / RGS
#define BCAP 12000       // bucket capacity per (sg,range); mean 10000
#define CHUNKA 25        // edge chunks per sg in binA; 320000/25 = 12800 edges/block

static __device__ __forceinline__ float sigmf(float x){ return 1.0f/(1.0f + __expf(-x)); }

// float -> bf16 bits, round-nearest-even
static __device__ __forceinline__ unsigned short f2bf(float f){
    union { float f; unsigned u; } v; v.f = f;
    unsigned r = v.u + 0x7FFF + ((v.u >> 16) & 1);
    return (unsigned short)(r >> 16);
}

typedef short bf16x8 __attribute__((ext_vector_type(8)));
typedef float f32x4  __attribute__((ext_vector_type(4)));

// ---------------- Phase A: bin edges into 32 dst-range buckets, packed (dstLoc<<15)|src ----------------

__global__ __launch_bounds__(256) void binA_kernel(const int* __restrict__ ei,
                                                   int* __restrict__ bcur,
                                                   int* __restrict__ bkt){
    __shared__ int wcnt[4*RGS];
    __shared__ int wb[4*RGS];
    int chunk = blockIdx.x, sg = blockIdx.y;
    int tid = threadIdx.x, w = tid >> 6;
    const int* srcp = ei + (size_t)(sg*2 + 0)*EE;
    const int* dstp = ei + (size_t)(sg*2 + 1)*EE;
    int start = chunk*12800, end = start + 12800;

    for (int it = 0; it < 13; ++it){
        if (tid < 4*RGS) wcnt[tid] = 0;
        __syncthreads();
        int e = start + it*1024 + tid*4;
        bool valid = e < end;
        int d_[4], s_[4], r_[4], dl_[4], rk_[4];
        if (valid){
            int4 d4 = *(const int4*)&dstp[e];
            int4 s4 = *(const int4*)&srcp[e];
            d_[0]=d4.x; d_[1]=d4.y; d_[2]=d4.z; d_[3]=d4.w;
            s_[0]=s4.x; s_[1]=s4.y; s_[2]=s4.z; s_[3]=s4.w;
            #pragma unroll
            for (int j = 0; j < 4; ++j){
                int r = d_[j] / RNODES2;
                r_[j]  = r;
                dl_[j] = d_[j] - r*RNODES2;
                rk_[j] = atomicAdd(&wcnt[w*RGS + r], 1);
            }
        }
        __syncthreads();
        if (tid < RGS){
            int c0 = wcnt[0*RGS+tid], c1 = wcnt[1*RGS+tid];
            int c2 = wcnt[2*RGS+tid], c3 = wcnt[3*RGS+tid];
            int tot = c0+c1+c2+c3;
            int gb = 0;
            if (tot > 0) gb = atomicAdd(&bcur[sg*RGS + tid], tot);
            wb[0*RGS+tid] = gb;
            wb[1*RGS+tid] = gb + c0;
            wb[2*RGS+tid] = gb + c0 + c1;
            wb[3*RGS+tid] = gb + c0 + c1 + c2;
        }
        __syncthreads();
        if (valid){
            #pragma unroll
            for (int j = 0; j < 4; ++j){
                int pos = wb[w*RGS + r_[j]] + rk_[j];
                if (pos < BCAP)
                    bkt[(size_t)(sg*RGS + r_[j])*BCAP + pos] = (dl_[j] << 15) | s_[j];
            }
        }
    }
}

// ---------------- Phase B: per (sg,range): hist -> scan -> CSR segment -> in-place dump ----------------

__global__ __launch_bounds__(256) void buildB_kernel(int* __restrict__ bkt,
                                                     const int* __restrict__ bcur,
                                                     int* __restrict__ off2,
                                                     int* __restrict__ deg2){
    __shared__ int hist[RNODES2];
    __shared__ int pref[RNODES2];
    __shared__ int seg[BCAP];
    __shared__ int sums[256];
    int sg = blockIdx.x / RGS, rg = blockIdx.x % RGS;
    int tid = threadIdx.x;
    int cnt = bcur[sg*RGS + rg];
    if (cnt > BCAP) cnt = BCAP;
    size_t base = (size_t)(sg*RGS + rg)*BCAP;

    for (int i = tid; i < RNODES2; i += 256) hist[i] = 0;
    __syncthreads();
    for (int j = tid; j < cnt; j += 256)
        atomicAdd(&hist[bkt[base + j] >> 15], 1);
    __syncthreads();

    int lo = tid*3, hi = min(lo+3, RNODES2);
    int s = 0;
    for (int i = lo; i < hi; ++i) s += hist[i];
    sums[tid] = s; __syncthreads();
    for (int ofs = 1; ofs < 256; ofs <<= 1){
        int v = (tid >= ofs) ? sums[tid-ofs] : 0;
        __syncthreads();
        sums[tid] += v;
        __syncthreads();
    }
    int run = sums[tid] - s;
    int gnode = sg*NN + rg*RNODES2;
    for (int i = lo; i < hi; ++i){
        pref[i] = run;
        off2[gnode + i] = (int)base + run;
        deg2[gnode + i] = hist[i];
        run += hist[i];
    }
    __syncthreads();

    for (int j = tid; j < cnt; j += 256){
        int p = bkt[base + j];
        int slot = atomicAdd(&pref[p >> 15], 1);
        seg[slot] = p & 0x7FFF;
    }
    __syncthreads();

    for (int j = tid; j < cnt; j += 256) bkt[base + j] = seg[j];
}

// ---------------- x -> bf16 convert ----------------

__global__ __launch_bounds__(256) void convert_kernel(const float* __restrict__ x,
                                                      unsigned short* __restrict__ xb){
    int idx = blockIdx.x*256 + threadIdx.x;
    if (idx >= SG*NN*16) return;
    float4 v = ((const float4*)x)[idx];
    uint2 pk;
    pk.x = (unsigned)f2bf(v.x) | ((unsigned)f2bf(v.y) << 16);
    pk.y = (unsigned)f2bf(v.z) | ((unsigned)f2bf(v.w) << 16);
    ((uint2*)xb)[idx] = pk;
}

// ---------------- weight prep: all bf16, [col][k] layouts ----------------
// WL1/WL2: [g][64 col][128 k], k<64 = Wl rows (mean), k>=64 = Wr rows (x)
// Wt: [256 col][128 k] (Wih || Whh);  bc = bih + bhh

__global__ __launch_bounds__(256) void wprep2_kernel(const float* __restrict__ W1l,
                                                     const float* __restrict__ W1r,
                                                     const float* __restrict__ W2l,
                                                     const float* __restrict__ W2r,
                                                     const float* __restrict__ Wih,
                                                     const float* __restrict__ Whh,
                                                     const float* __restrict__ bih,
                                                     const float* __restrict__ bhh,
                                                     unsigned short* __restrict__ WL1,
                                                     unsigned short* __restrict__ WL2,
                                                     unsigned short* __restrict__ Wt,
                                                     float* __restrict__ bc){
    int idx = blockIdx.x*256 + threadIdx.x;
    if (idx < 24576){
        int g = idx >> 13, rem = idx & 8191, col = rem >> 7, k = rem & 127;
        float v = (k < 64) ? W1l[((size_t)g*64 + k)*64 + col]
                           : W1r[((size_t)g*64 + (k-64))*64 + col];
        WL1[idx] = f2bf(v);
    } else if (idx < 49152){
        int t = idx - 24576;
        int g = t >> 13, rem = t & 8191, col = rem >> 7, k = rem & 127;
        float v = (k < 64) ? W2l[((size_t)g*64 + k)*64 + col]
                           : W2r[((size_t)g*64 + (k-64))*64 + col];
        WL2[t] = f2bf(v);
    } else if (idx < 81920){
        int t = idx - 49152;
        int col = t >> 7, k = t & 127;
        float v = (k < 64) ? Wih[col*64 + k] : Whh[col*64 + (k - 64)];
        Wt[t] = f2bf(v);
    } else if (idx < 82176){
        int t = idx - 81920;
        bc[t] = bih[t] + bhh[t];
    }
}

// ---------------- SAGE layer: bf16 gather-mean + MFMA GEMM + tanh -> bf16 out ----------------
// sA[r][k] bf16, pitch 136 (272 B = 17*16 -> rows 16B-aligned, bank stride 4 -> 2-way free)
// k<64: mean, k>=64: x.  B = WL[g][col][128] from global (L1-hot).

#define LDA 136

__global__ __launch_bounds__(256) void layer_kernel(const unsigned short* __restrict__ xb,
                                                    const int* __restrict__ off2,
                                                    const int* __restrict__ deg2,
                                                    const int* __restrict__ csr,
                                                    const unsigned short* __restrict__ WL,
                                                    const float* __restrict__ bias,
                                                    unsigned short* __restrict__ outb){
    __shared__ unsigned short sA[64*LDA];  // 17.4 KB
    __shared__ unsigned short sO[64*80];   // 10.2 KB
    int tile = blockIdx.x, sg = blockIdx.y;
    int g = sg % G;
    int tid = threadIdx.x;
    int row0 = tile*64;
    const unsigned short* inb = xb + (size_t)sg*NN*D;

    // stage x tile (bf16, 16 B chunks) into sA[r][64..127]
    for (int idx = tid; idx < 64*8; idx += 256){
        int r = idx >> 3, c = idx & 7;
        int i = row0 + r;
        uint4 v = {0,0,0,0};
        if (i < NN) v = *(const uint4*)&inb[(size_t)i*D + c*8];
        *(uint4*)&sA[r*LDA + 64 + c*8] = v;
    }

    // aggregation: 8 groups x 8 lanes; each group owns one output row, serial over
    // its neighbors (8 independent 16 B gathers in flight), no cross-lane reduce.
    {
        int wave = tid >> 6, lane = tid & 63;
        int gp = lane >> 3, fl = lane & 7;
        int i0 = row0 + wave*16;
        int ii = min(i0 + (lane & 15), NN-1);
        int val = (lane < 16) ? off2[sg*NN + ii] : ((lane < 32) ? deg2[sg*NN + ii] : 0);
        #pragma unroll
        for (int rb = 0; rb < 2; ++rb){
            int rloc = rb*8 + gp;
            int a  = __shfl(val, rloc, 64);
            int dg = __shfl(val, 16 + rloc, 64);
            if (i0 + rloc >= NN) dg = 0;
            float acc[8] = {0,0,0,0,0,0,0,0};
            for (int base = 0; base < dg; base += 8){
                int myi = 0;
                if (base + fl < dg) myi = csr[a + base + fl];
                #pragma unroll
                for (int j = 0; j < 8; ++j){
                    int nj = __shfl(myi, gp*8 + j, 64);
                    if (base + j < dg){
                        uint4 v = *(const uint4*)&inb[(size_t)nj*D + fl*8];
                        acc[0] += __uint_as_float(v.x << 16);
                        acc[1] += __uint_as_float(v.x & 0xFFFF0000u);
                        acc[2] += __uint_as_float(v.y << 16);
                        acc[3] += __uint_as_float(v.y & 0xFFFF0000u);
                        acc[4] += __uint_as_float(v.z << 16);
                        acc[5] += __uint_as_float(v.z & 0xFFFF0000u);
                        acc[6] += __uint_as_float(v.w << 16);
                        acc[7] += __uint_as_float(v.w & 0xFFFF0000u);
                    }
                }
            }
            float inv = (dg > 0) ? (1.0f/(float)dg) : 0.0f;
            uint4 pk;
            pk.x = (unsigned)f2bf(acc[0]*inv) | ((unsigned)f2bf(acc[1]*inv) << 16);
            pk.y = (unsigned)f2bf(acc[2]*inv) | ((unsigned)f2bf(acc[3]*inv) << 16);
            pk.z = (unsigned)f2bf(acc[4]*inv) | ((unsigned)f2bf(acc[5]*inv) << 16);
            pk.w = (unsigned)f2bf(acc[6]*inv) | ((unsigned)f2bf(acc[7]*inv) << 16);
            *(uint4*)&sA[(wave*16 + rloc)*LDA + fl*8] = pk;
        }
    }
    __syncthreads();

    // MFMA: 16 rows/wave, K=128 (mean||x), 64 cols in 4 tiles
    {
        int wave = tid >> 6, lane = tid & 63;
        int n0 = lane & 15, q = lane >> 4;
        int rbase = wave*16;
        const unsigned short* WLg = WL + (size_t)g*64*128;
        f32x4 accv[4];
        #pragma unroll
        for (int ct = 0; ct < 4; ++ct) accv[ct] = (f32x4){0.f,0.f,0.f,0.f};
        #pragma unroll
        for (int kc = 0; kc < 4; ++kc){
            bf16x8 af = *(const bf16x8*)&sA[(rbase + n0)*LDA + kc*32 + q*8];
            #pragma unroll
            for (int ct = 0; ct < 4; ++ct){
                bf16x8 bfr = *(const bf16x8*)&WLg[(ct*16 + n0)*128 + kc*32 + q*8];
                accv[ct] = __builtin_amdgcn_mfma_f32_16x16x32_bf16(af, bfr, accv[ct], 0, 0, 0);
            }
        }
        #pragma unroll
        for (int ct = 0; ct < 4; ++ct){
            float bv = bias[g*64 + ct*16 + n0];
            #pragma unroll
            for (int reg = 0; reg < 4; ++reg){
                int r = rbase + q*4 + reg;
                sO[r*80 + ct*16 + n0] = f2bf(tanhf(accv[ct][reg] + bv));
            }
        }
    }
    __syncthreads();

    for (int idx = tid; idx < 64*8; idx += 256){
        int r = idx >> 3, c = idx & 7;
        int i = row0 + r;
        if (i < NN){
            uint4 v = *(const uint4*)&sO[r*80 + c*8];
            *(uint4*)&outb[((size_t)sg*NN + i)*D + c*8] = v;
        }
    }
}

// ---------------- LSTM: 3 steps fused, MFMA bf16, reads bf16 h2 ----------------

__global__ __launch_bounds__(256) void lstm_kernel(const unsigned short* __restrict__ h2b,
                                                   const unsigned short* __restrict__ Wt,
                                                   const float* __restrict__ bc,
                                                   float* __restrict__ out){
    __shared__ unsigned short sA[64*LDA];
    __shared__ float sO[64*68];
    int tid = threadIdx.x;
    int b0 = blockIdx.x * 64;
    int wave = tid >> 6, lane = tid & 63;
    int n0 = lane & 15, q = lane >> 4;
    int rbase = wave*16;

    float bb[4][4];
    #pragma unroll
    for (int T = 0; T < 4; ++T)
        #pragma unroll
        for (int m = 0; m < 4; ++m)
            bb[T][m] = bc[T*64 + n0 + 16*m];

    float c[4][4];
    #pragma unroll
    for (int i = 0; i < 4; ++i)
        #pragma unroll
        for (int m = 0; m < 4; ++m) c[i][m] = 0.0f;

    for (int t = 0; t < G; ++t){
        // stage x_t (already bf16): 16 B chunks
        for (int idx = tid; idx < 64*8; idx += 256){
            int r = idx >> 3, cch = idx & 7;
            int b = b0 + r;
            int s = b / NN, n = b - s*NN;
            uint4 v = *(const uint4*)&h2b[((size_t)(s*G + t)*NN + n)*D + cch*8];
            *(uint4*)&sA[r*LDA + cch*8] = v;
        }
        __syncthreads();

        int nkc = (t == 0) ? 2 : 4;
        f32x4 accv[16];
        #pragma unroll
        for (int ct = 0; ct < 16; ++ct) accv[ct] = (f32x4){0.f,0.f,0.f,0.f};

        #pragma unroll 1
        for (int kc = 0; kc < nkc; ++kc){
            bf16x8 af = *(const bf16x8*)&sA[(rbase + n0)*LDA + kc*32 + q*8];
            #pragma unroll
            for (int ct = 0; ct < 16; ++ct){
                bf16x8 bfr = *(const bf16x8*)&Wt[(ct*16 + n0)*128 + kc*32 + q*8];
                accv[ct] = __builtin_amdgcn_mfma_f32_16x16x32_bf16(af, bfr, accv[ct], 0, 0, 0);
            }
        }
        __syncthreads();

        #pragma unroll
        for (int reg = 0; reg < 4; ++reg){
            int r = rbase + q*4 + reg;
            #pragma unroll
            for (int m = 0; m < 4; ++m){
                float ig = sigmf(accv[0*4 + m][reg] + bb[0][m]);
                float fg = sigmf(accv[1*4 + m][reg] + bb[1][m]);
                float gg = tanhf(accv[2*4 + m][reg] + bb[2][m]);
                float og = sigmf(accv[3*4 + m][reg] + bb[3][m]);
                float cn = fg*c[reg][m] + ig*gg;
                c[reg][m] = cn;
                float hv = og * tanhf(cn);
                if (t < G-1) sA[r*LDA + 64 + n0 + 16*m] = f2bf(hv);
                else         sO[r*68 + n0 + 16*m] = hv;
            }
        }
    }

    __syncthreads();
    for (int idx = tid; idx < 64*16; idx += 256){
        int r = idx >> 4, fq = idx & 15;
        float4 v = *(const float4*)&sO[r*68 + fq*4];
        *(float4*)&out[(size_t)(b0 + r)*D + fq*4] = v;
    }
}

// ---------------- host ----------------

extern "C" void kernel_launch(void* const* d_in, const int* in_sizes, int n_in,
                              void* d_out, int out_size, void* d_ws, size_t ws_size,
                              hipStream_t stream) {
    const float* x   = (const float*)d_in[0];
    const int*   ei  = (const int*)  d_in[1];
    const float* W1l = (const float*)d_in[2];
    const float* W1r = (const float*)d_in[3];
    const float* b1  = (const float*)d_in[4];
    const float* W2l = (const float*)d_in[5];
    const float* W2r = (const float*)d_in[6];
    const float* b2  = (const float*)d_in[7];
    const float* Wih = (const float*)d_in[8];
    const float* Whh = (const float*)d_in[9];
    const float* bih = (const float*)d_in[10];
    const float* bhh = (const float*)d_in[11];
    float* out = (float*)d_out;

    char* ws = (char*)d_ws;
    size_t cur = 0;
    auto alloc = [&](size_t bytes)->void*{
        cur = (cur + 255) & ~(size_t)255;
        void* p = ws + cur; cur += bytes; return p;
    };
    int*   bkt  = (int*)alloc((size_t)SG*RGS*BCAP*4);   // buckets, then CSR in place
    int*   bcur = (int*)alloc((size_t)SG*RGS*4);
    int*   off2 = (int*)alloc((size_t)SG*NN*4);
    int*   deg2 = (int*)alloc((size_t)SG*NN*4);
    unsigned short* xb  = (unsigned short*)alloc((size_t)SG*NN*D*2);
    unsigned short* h1b = (unsigned short*)alloc((size_t)SG*NN*D*2);
    unsigned short* h2b = (unsigned short*)alloc((size_t)SG*NN*D*2);
    unsigned short* WL1 = (unsigned short*)alloc((size_t)G*64*128*2);
    unsigned short* WL2 = (unsigned short*)alloc((size_t)G*64*128*2);
    unsigned short* Wt  = (unsigned short*)alloc((size_t)256*128*2);
    float* bc   = (float*)alloc((size_t)256*4);
    (void)ws_size; (void)in_sizes; (void)n_in; (void)out_size;

    (void)hipMemsetAsync(bcur, 0, (size_t)SG*RGS*4, stream);

    convert_kernel<<<(SG*NN*16 + 255)/256, 256, 0, stream>>>(x, xb);
    binA_kernel  <<<dim3(CHUNKA, SG), 256, 0, stream>>>(ei, bcur, bkt);
    buildB_kernel<<<SG*RGS, 256, 0, stream>>>(bkt, bcur, off2, deg2);
    wprep2_kernel<<<321, 256, 0, stream>>>(W1l, W1r, W2l, W2r, Wih, Whh, bih, bhh,
                                           WL1, WL2, Wt, bc);

    dim3 lgrid((NN + 63)/64, SG);
    layer_kernel<<<lgrid, 256, 0, stream>>>(xb,  off2, deg2, bkt, WL1, b1, h1b);
    layer_kernel<<<lgrid, 256, 0, stream>>>(h1b, off2, deg2, bkt, WL2, b2, h2b);

    lstm_kernel <<<(S*NN)/64, 256, 0, stream>>>(h2b, Wt, bc, out);
}

// Round 9
// 506.555 us; speedup vs baseline: 2.1937x; 1.0379x over previous
//
#include <hip/hip_runtime.h>
#include <math.h>

#define S 4
#define G 3
#define NN 20000
#define EE 320000
#define D 64
#define SG (S*G)

#define RGS 32           // dst-ranges per graph
#define RNODES2 625      // NN / RGS
#define BCAP 12000       // bucket capacity per (sg,range); mean 10000
#define CHUNKA 25        // edge chunks per sg in binA; 320000/25 = 12800 edges/block

static __device__ __forceinline__ float sigmf(float x){ return 1.0f/(1.0f + __expf(-x)); }
// fast tanh via hardware exp: 1 - 2/(e^{2x}+1); saturates correctly at +/-inf
static __device__ __forceinline__ float tanhf_fast(float x){
    float t = __expf(2.0f*x);
    return 1.0f - 2.0f/(t + 1.0f);
}

// float -> bf16 bits, round-nearest-even
static __device__ __forceinline__ unsigned short f2bf(float f){
    union { float f; unsigned u; } v; v.f = f;
    unsigned r = v.u + 0x7FFF + ((v.u >> 16) & 1);
    return (unsigned short)(r >> 16);
}

typedef short bf16x8 __attribute__((ext_vector_type(8)));
typedef float f32x4  __attribute__((ext_vector_type(4)));

// ---------------- Phase A: bin edges into 32 dst-range buckets, packed (dstLoc<<15)|src ----------------

__global__ __launch_bounds__(256) void binA_kernel(const int* __restrict__ ei,
                                                   int* __restrict__ bcur,
                                                   int* __restrict__ bkt){
    __shared__ int wcnt[4*RGS];
    __shared__ int wb[4*RGS];
    int chunk = blockIdx.x, sg = blockIdx.y;
    int tid = threadIdx.x, w = tid >> 6;
    const int* srcp = ei + (size_t)(sg*2 + 0)*EE;
    const int* dstp = ei + (size_t)(sg*2 + 1)*EE;
    int start = chunk*12800, end = start + 12800;

    for (int it = 0; it < 13; ++it){
        if (tid < 4*RGS) wcnt[tid] = 0;
        __syncthreads();
        int e = start + it*1024 + tid*4;
        bool valid = e < end;
        int d_[4], s_[4], r_[4], dl_[4], rk_[4];
        if (valid){
            int4 d4 = *(const int4*)&dstp[e];
            int4 s4 = *(const int4*)&srcp[e];
            d_[0]=d4.x; d_[1]=d4.y; d_[2]=d4.z; d_[3]=d4.w;
            s_[0]=s4.x; s_[1]=s4.y; s_[2]=s4.z; s_[3]=s4.w;
            #pragma unroll
            for (int j = 0; j < 4; ++j){
                int r = d_[j] / RNODES2;
                r_[j]  = r;
                dl_[j] = d_[j] - r*RNODES2;
                rk_[j] = atomicAdd(&wcnt[w*RGS + r], 1);
            }
        }
        __syncthreads();
        if (tid < RGS){
            int c0 = wcnt[0*RGS+tid], c1 = wcnt[1*RGS+tid];
            int c2 = wcnt[2*RGS+tid], c3 = wcnt[3*RGS+tid];
            int tot = c0+c1+c2+c3;
            int gb = 0;
            if (tot > 0) gb = atomicAdd(&bcur[sg*RGS + tid], tot);
            wb[0*RGS+tid] = gb;
            wb[1*RGS+tid] = gb + c0;
            wb[2*RGS+tid] = gb + c0 + c1;
            wb[3*RGS+tid] = gb + c0 + c1 + c2;
        }
        __syncthreads();
        if (valid){
            #pragma unroll
            for (int j = 0; j < 4; ++j){
                int pos = wb[w*RGS + r_[j]] + rk_[j];
                if (pos < BCAP)
                    bkt[(size_t)(sg*RGS + r_[j])*BCAP + pos] = (dl_[j] << 15) | s_[j];
            }
        }
    }
}

// ---------------- Phase B: per (sg,range): hist -> scan -> CSR segment -> in-place dump ----------------

__global__ __launch_bounds__(256) void buildB_kernel(int* __restrict__ bkt,
                                                     const int* __restrict__ bcur,
                                                     int* __restrict__ off2,
                                                     int* __restrict__ deg2){
    __shared__ int hist[RNODES2];
    __shared__ int pref[RNODES2];
    __shared__ int seg[BCAP];
    __shared__ int sums[256];
    int sg = blockIdx.x / RGS, rg = blockIdx.x % RGS;
    int tid = threadIdx.x;
    int cnt = bcur[sg*RGS + rg];
    if (cnt > BCAP) cnt = BCAP;
    size_t base = (size_t)(sg*RGS + rg)*BCAP;

    for (int i = tid; i < RNODES2; i += 256) hist[i] = 0;
    __syncthreads();
    for (int j = tid; j < cnt; j += 256)
        atomicAdd(&hist[bkt[base + j] >> 15], 1);
    __syncthreads();

    int lo = tid*3, hi = min(lo+3, RNODES2);
    int s = 0;
    for (int i = lo; i < hi; ++i) s += hist[i];
    sums[tid] = s; __syncthreads();
    for (int ofs = 1; ofs < 256; ofs <<= 1){
        int v = (tid >= ofs) ? sums[tid-ofs] : 0;
        __syncthreads();
        sums[tid] += v;
        __syncthreads();
    }
    int run = sums[tid] - s;
    int gnode = sg*NN + rg*RNODES2;
    for (int i = lo; i < hi; ++i){
        pref[i] = run;
        off2[gnode + i] = (int)base + run;
        deg2[gnode + i] = hist[i];
        run += hist[i];
    }
    __syncthreads();

    for (int j = tid; j < cnt; j += 256){
        int p = bkt[base + j];
        int slot = atomicAdd(&pref[p >> 15], 1);
        seg[slot] = p & 0x7FFF;
    }
    __syncthreads();

    for (int j = tid; j < cnt; j += 256) bkt[base + j] = seg[j];
}

// ---------------- x -> bf16 convert ----------------

__global__ __launch_bounds__(256) void convert_kernel(const float* __restrict__ x,
                                                      unsigned short* __restrict__ xb){
    int idx = blockIdx.x*256 + threadIdx.x;
    if (idx >= SG*NN*16) return;
    float4 v = ((const float4*)x)[idx];
    uint2 pk;
    pk.x = (unsigned)f2bf(v.x) | ((unsigned)f2bf(v.y) << 16);
    pk.y = (unsigned)f2bf(v.z) | ((unsigned)f2bf(v.w) << 16);
    ((uint2*)xb)[idx] = pk;
}

// ---------------- weight prep: all bf16, [col][k] layouts ----------------

__global__ __launch_bounds__(256) void wprep2_kernel(const float* __restrict__ W1l,
                                                     const float* __restrict__ W1r,
                                                     const float* __restrict__ W2l,
                                                     const float* __restrict__ W2r,
                                                     const float* __restrict__ Wih,
                                                     const float* __restrict__ Whh,
                                                     const float* __restrict__ bih,
                                                     const float* __restrict__ bhh,
                                                     unsigned short* __restrict__ WL1,
                                                     unsigned short* __restrict__ WL2,
                                                     unsigned short* __restrict__ Wt,
                                                     float* __restrict__ bc){
    int idx = blockIdx.x*256 + threadIdx.x;
    if (idx < 24576){
        int g = idx >> 13, rem = idx & 8191, col = rem >> 7, k = rem & 127;
        float v = (k < 64) ? W1l[((size_t)g*64 + k)*64 + col]
                           : W1r[((size_t)g*64 + (k-64))*64 + col];
        WL1[idx] = f2bf(v);
    } else if (idx < 49152){
        int t = idx - 24576;
        int g = t >> 13, rem = t & 8191, col = rem >> 7, k = rem & 127;
        float v = (k < 64) ? W2l[((size_t)g*64 + k)*64 + col]
                           : W2r[((size_t)g*64 + (k-64))*64 + col];
        WL2[t] = f2bf(v);
    } else if (idx < 81920){
        int t = idx - 49152;
        int col = t >> 7, k = t & 127;
        float v = (k < 64) ? Wih[col*64 + k] : Whh[col*64 + (k - 64)];
        Wt[t] = f2bf(v);
    } else if (idx < 82176){
        int t = idx - 81920;
        bc[t] = bih[t] + bhh[t];
    }
}

// ---------------- SAGE layer: barrier-free. Per-wave: gather-mean -> wave LDS slice;
// x a-frags direct from global; MFMA K=128 (mean||x); tanh; bf16 out via wave slice. ----------------
// Wave slice pitch 72 ushort = 144 B (16B-aligned; bank stagger -> 2-way max on b128 reads).

#define WP 72

__global__ __launch_bounds__(256) void layer_kernel(const unsigned short* __restrict__ xb,
                                                    const int* __restrict__ off2,
                                                    const int* __restrict__ deg2,
                                                    const int* __restrict__ csr,
                                                    const unsigned short* __restrict__ WL,
                                                    const float* __restrict__ bias,
                                                    unsigned short* __restrict__ outb){
    __shared__ unsigned short sM[4][16*WP];  // mean slices, 9.2 KB
    __shared__ unsigned short sO[4][16*WP];  // out slices,  9.2 KB
    int tile = blockIdx.x, sg = blockIdx.y;
    int g = sg % G;
    int tid = threadIdx.x;
    int row0 = tile*64;
    const unsigned short* inb = xb + (size_t)sg*NN*D;

    int wave = tid >> 6, lane = tid & 63;
    int i0 = row0 + wave*16;

    // aggregation: 8 groups x 8 lanes; group owns one row; 8 gathers in flight
    {
        int gp = lane >> 3, fl = lane & 7;
        int ii = min(i0 + (lane & 15), NN-1);
        int val = (lane < 16) ? off2[sg*NN + ii] : ((lane < 32) ? deg2[sg*NN + ii] : 0);
        #pragma unroll
        for (int rb = 0; rb < 2; ++rb){
            int rloc = rb*8 + gp;
            int a  = __shfl(val, rloc, 64);
            int dg = __shfl(val, 16 + rloc, 64);
            if (i0 + rloc >= NN) dg = 0;
            float acc[8] = {0,0,0,0,0,0,0,0};
            for (int base = 0; base < dg; base += 8){
                int myi = 0;
                if (base + fl < dg) myi = csr[a + base + fl];
                #pragma unroll
                for (int j = 0; j < 8; ++j){
                    int nj = __shfl(myi, gp*8 + j, 64);
                    if (base + j < dg){
                        uint4 v = *(const uint4*)&inb[(size_t)nj*D + fl*8];
                        acc[0] += __uint_as_float(v.x << 16);
                        acc[1] += __uint_as_float(v.x & 0xFFFF0000u);
                        acc[2] += __uint_as_float(v.y << 16);
                        acc[3] += __uint_as_float(v.y & 0xFFFF0000u);
                        acc[4] += __uint_as_float(v.z << 16);
                        acc[5] += __uint_as_float(v.z & 0xFFFF0000u);
                        acc[6] += __uint_as_float(v.w << 16);
                        acc[7] += __uint_as_float(v.w & 0xFFFF0000u);
                    }
                }
            }
            float inv = (dg > 0) ? (1.0f/(float)dg) : 0.0f;
            uint4 pk;
            pk.x = (unsigned)f2bf(acc[0]*inv) | ((unsigned)f2bf(acc[1]*inv) << 16);
            pk.y = (unsigned)f2bf(acc[2]*inv) | ((unsigned)f2bf(acc[3]*inv) << 16);
            pk.z = (unsigned)f2bf(acc[4]*inv) | ((unsigned)f2bf(acc[5]*inv) << 16);
            pk.w = (unsigned)f2bf(acc[6]*inv) | ((unsigned)f2bf(acc[7]*inv) << 16);
            *(uint4*)&sM[wave][rloc*WP + fl*8] = pk;
        }
    }
    // no barrier: consumers are this same wave (lgkmcnt ordering)

    int n0 = lane & 15, q = lane >> 4;
    const unsigned short* WLg = WL + (size_t)g*64*128;
    f32x4 accv[4];
    #pragma unroll
    for (int ct = 0; ct < 4; ++ct) accv[ct] = (f32x4){0.f,0.f,0.f,0.f};
    int irow = min(i0 + n0, NN-1);
    #pragma unroll
    for (int kc = 0; kc < 4; ++kc){
        bf16x8 af;
        if (kc < 2) af = *(const bf16x8*)&sM[wave][n0*WP + kc*32 + q*8];
        else        af = *(const bf16x8*)&inb[(size_t)irow*D + (kc-2)*32 + q*8];
        #pragma unroll
        for (int ct = 0; ct < 4; ++ct){
            bf16x8 bfr = *(const bf16x8*)&WLg[(ct*16 + n0)*128 + kc*32 + q*8];
            accv[ct] = __builtin_amdgcn_mfma_f32_16x16x32_bf16(af, bfr, accv[ct], 0, 0, 0);
        }
    }
    #pragma unroll
    for (int ct = 0; ct < 4; ++ct){
        float bv = bias[g*64 + ct*16 + n0];
        #pragma unroll
        for (int reg = 0; reg < 4; ++reg)
            sO[wave][(q*4+reg)*WP + ct*16 + n0] = f2bf(tanhf_fast(accv[ct][reg] + bv));
    }
    // intra-wave writeback: 2 passes of 8 rows x 8 chunk-lanes
    #pragma unroll
    for (int pass = 0; pass < 2; ++pass){
        int rloc = pass*8 + (lane >> 3), chunk = lane & 7;
        int i = i0 + rloc;
        if (i < NN){
            uint4 v = *(const uint4*)&sO[wave][rloc*WP + chunk*8];
            *(uint4*)&outb[((size_t)sg*NN + i)*D + chunk*8] = v;
        }
    }
}

// ---------------- LSTM: barrier-free, 3 steps fused, MFMA bf16 ----------------
// x a-frags direct from global h2b; h exchanged via per-wave LDS slice; c in regs;
// final output as direct dword stores.

__global__ __launch_bounds__(256) void lstm_kernel(const unsigned short* __restrict__ h2b,
                                                   const unsigned short* __restrict__ Wt,
                                                   const float* __restrict__ bc,
                                                   float* __restrict__ out){
    __shared__ unsigned short sH[4][16*WP];  // 9.2 KB
    int tid = threadIdx.x;
    int b0 = blockIdx.x * 64;
    int wave = tid >> 6, lane = tid & 63;
    int n0 = lane & 15, q = lane >> 4;
    int rbase = wave*16;

    float bb[4][4];
    #pragma unroll
    for (int T = 0; T < 4; ++T)
        #pragma unroll
        for (int m = 0; m < 4; ++m)
            bb[T][m] = bc[T*64 + n0 + 16*m];

    float c[4][4];
    #pragma unroll
    for (int i = 0; i < 4; ++i)
        #pragma unroll
        for (int m = 0; m < 4; ++m) c[i][m] = 0.0f;

    // this lane's A-row global position (fixed across t)
    int b = b0 + rbase + n0;
    int s = b / NN, n = b - s*NN;

    for (int t = 0; t < G; ++t){
        int nkc = (t == 0) ? 2 : 4;
        f32x4 accv[16];
        #pragma unroll
        for (int ct = 0; ct < 16; ++ct) accv[ct] = (f32x4){0.f,0.f,0.f,0.f};

        const unsigned short* xrow = &h2b[((size_t)(s*G + t)*NN + n)*D];
        #pragma unroll 1
        for (int kc = 0; kc < nkc; ++kc){
            bf16x8 af;
            if (kc < 2) af = *(const bf16x8*)&xrow[kc*32 + q*8];
            else        af = *(const bf16x8*)&sH[wave][n0*WP + (kc-2)*32 + q*8];
            #pragma unroll
            for (int ct = 0; ct < 16; ++ct){
                bf16x8 bfr = *(const bf16x8*)&Wt[(ct*16 + n0)*128 + kc*32 + q*8];
                accv[ct] = __builtin_amdgcn_mfma_f32_16x16x32_bf16(af, bfr, accv[ct], 0, 0, 0);
            }
        }

        #pragma unroll
        for (int reg = 0; reg < 4; ++reg){
            int rloc = q*4 + reg;
            #pragma unroll
            for (int m = 0; m < 4; ++m){
                float ig = sigmf(accv[0*4 + m][reg] + bb[0][m]);
                float fg = sigmf(accv[1*4 + m][reg] + bb[1][m]);
                float gg = tanhf_fast(accv[2*4 + m][reg] + bb[2][m]);
                float og = sigmf(accv[3*4 + m][reg] + bb[3][m]);
                float cn = fg*c[reg][m] + ig*gg;
                c[reg][m] = cn;
                float hv = og * tanhf_fast(cn);
                if (t < G-1) sH[wave][rloc*WP + n0 + 16*m] = f2bf(hv);
                else         out[(size_t)(b0 + rbase + rloc)*D + n0 + 16*m] = hv;
            }
        }
        // intra-wave LDS RAW/WAR handled by lgkmcnt; no barriers anywhere
    }
}

// ---------------- host ----------------

extern "C" void kernel_launch(void* const* d_in, const int* in_sizes, int n_in,
                              void* d_out, int out_size, void* d_ws, size_t ws_size,
                              hipStream_t stream) {
    const float* x   = (const float*)d_in[0];
    const int*   ei  = (const int*)  d_in[1];
    const float* W1l = (const float*)d_in[2];
    const float* W1r = (const float*)d_in[3];
    const float* b1  = (const float*)d_in[4];
    const float* W2l = (const float*)d_in[5];
    const float* W2r = (const float*)d_in[6];
    const float* b2  = (const float*)d_in[7];
    const float* Wih = (const float*)d_in[8];
    const float* Whh = (const float*)d_in[9];
    const float* bih = (const float*)d_in[10];
    const float* bhh = (const float*)d_in[11];
    float* out = (float*)d_out;

    char* ws = (char*)d_ws;
    size_t cur = 0;
    auto alloc = [&](size_t bytes)->void*{
        cur = (cur + 255) & ~(size_t)255;
        void* p = ws + cur; cur += bytes; return p;
    };
    int*   bkt  = (int*)alloc((size_t)SG*RGS*BCAP*4);   // buckets, then CSR in place
    int*   bcur = (int*)alloc((size_t)SG*RGS*4);
    int*   off2 = (int*)alloc((size_t)SG*NN*4);
    int*   deg2 = (int*)alloc((size_t)SG*NN*4);
    unsigned short* xb  = (unsigned short*)alloc((size_t)SG*NN*D*2);
    unsigned short* h1b = (unsigned short*)alloc((size_t)SG*NN*D*2);
    unsigned short* h2b = (unsigned short*)alloc((size_t)SG*NN*D*2);
    unsigned short* WL1 = (unsigned short*)alloc((size_t)G*64*128*2);
    unsigned short* WL2 = (unsigned short*)alloc((size_t)G*64*128*2);
    unsigned short* Wt  = (unsigned short*)alloc((size_t)256*128*2);
    float* bc   = (float*)alloc((size_t)256*4);
    (void)ws_size; (void)in_sizes; (void)n_in; (void)out_size;

    (void)hipMemsetAsync(bcur, 0, (size_t)SG*RGS*4, stream);

    convert_kernel<<<(SG*NN*16 + 255)/256, 256, 0, stream>>>(x, xb);
    binA_kernel  <<<dim3(CHUNKA, SG), 256, 0, stream>>>(ei, bcur, bkt);
    buildB_kernel<<<SG*RGS, 256, 0, stream>>>(bkt, bcur, off2, deg2);
    wprep2_kernel<<<321, 256, 0, stream>>>(W1l, W1r, W2l, W2r, Wih, Whh, bih, bhh,
                                           WL1, WL2, Wt, bc);

    dim3 lgrid((NN + 63)/64, SG);
    layer_kernel<<<lgrid, 256, 0, stream>>>(xb,  off2, deg2, bkt, WL1, b1, h1b);
    layer_kernel<<<lgrid, 256, 0, stream>>>(h1b, off2, deg2, bkt, WL2, b2, h2b);

    lstm_kernel <<<(S*NN)/64, 256, 0, stream>>>(h2b, Wt, bc, out);
}

// Round 10
// 430.486 us; speedup vs baseline: 2.5814x; 1.1767x over previous
//
#include <hip/hip_runtime.h>
#include <math.h>

#define S 4
#define G 3
#define NN 20000
#define EE 320000
#define D 64
#define SG (S*G)

#define RGS 32           // dst-ranges per graph
#define RNODES2 625      // NN / RGS
#define BCAP 12000       // bucket capacity per (sg,range); mean 10000
#define CHUNKA 100       // edge chunks per sg in binA; 320000/100 = 3200 edges/block

static __device__ __forceinline__ float rcpf(float x){ return __builtin_amdgcn_rcpf(x); }
static __device__ __forceinline__ float sigmf(float x){ return rcpf(1.0f + __expf(-x)); }
// fast tanh: 1 - 2/(e^{2x}+1), v_rcp for the divide; saturates correctly
static __device__ __forceinline__ float tanhf_fast(float x){
    float t = __expf(2.0f*x);
    return 1.0f - 2.0f*rcpf(t + 1.0f);
}

// float -> bf16 bits, round-nearest-even
static __device__ __forceinline__ unsigned short f2bf(float f){
    union { float f; unsigned u; } v; v.f = f;
    unsigned r = v.u + 0x7FFF + ((v.u >> 16) & 1);
    return (unsigned short)(r >> 16);
}

typedef short bf16x8 __attribute__((ext_vector_type(8)));
typedef float f32x4  __attribute__((ext_vector_type(4)));

// ---------------- Phase A: bin edges into 32 dst-range buckets, packed (dstLoc<<15)|src ----------------

__global__ __launch_bounds__(256) void binA_kernel(const int* __restrict__ ei,
                                                   int* __restrict__ bcur,
                                                   int* __restrict__ bkt){
    __shared__ int wcnt[4*RGS];
    __shared__ int wb[4*RGS];
    int chunk = blockIdx.x, sg = blockIdx.y;
    int tid = threadIdx.x, w = tid >> 6;
    const int* srcp = ei + (size_t)(sg*2 + 0)*EE;
    const int* dstp = ei + (size_t)(sg*2 + 1)*EE;
    const int EPC = EE/CHUNKA;               // 3200
    int start = chunk*EPC, end = start + EPC;

    for (int it = 0; it < (EPC + 1023)/1024; ++it){
        if (tid < 4*RGS) wcnt[tid] = 0;
        __syncthreads();
        int e = start + it*1024 + tid*4;
        bool valid = e < end;
        int d_[4], s_[4], r_[4], dl_[4], rk_[4];
        if (valid){
            int4 d4 = *(const int4*)&dstp[e];
            int4 s4 = *(const int4*)&srcp[e];
            d_[0]=d4.x; d_[1]=d4.y; d_[2]=d4.z; d_[3]=d4.w;
            s_[0]=s4.x; s_[1]=s4.y; s_[2]=s4.z; s_[3]=s4.w;
            #pragma unroll
            for (int j = 0; j < 4; ++j){
                int r = d_[j] / RNODES2;
                r_[j]  = r;
                dl_[j] = d_[j] - r*RNODES2;
                rk_[j] = atomicAdd(&wcnt[w*RGS + r], 1);
            }
        }
        __syncthreads();
        if (tid < RGS){
            int c0 = wcnt[0*RGS+tid], c1 = wcnt[1*RGS+tid];
            int c2 = wcnt[2*RGS+tid], c3 = wcnt[3*RGS+tid];
            int tot = c0+c1+c2+c3;
            int gb = 0;
            if (tot > 0) gb = atomicAdd(&bcur[sg*RGS + tid], tot);
            wb[0*RGS+tid] = gb;
            wb[1*RGS+tid] = gb + c0;
            wb[2*RGS+tid] = gb + c0 + c1;
            wb[3*RGS+tid] = gb + c0 + c1 + c2;
        }
        __syncthreads();
        if (valid){
            #pragma unroll
            for (int j = 0; j < 4; ++j){
                int pos = wb[w*RGS + r_[j]] + rk_[j];
                if (pos < BCAP)
                    bkt[(size_t)(sg*RGS + r_[j])*BCAP + pos] = (dl_[j] << 15) | s_[j];
            }
        }
    }
}

// ---------------- Phase B: per (sg,range): hist -> scan -> CSR segment -> in-place dump ----------------

__global__ __launch_bounds__(256) void buildB_kernel(int* __restrict__ bkt,
                                                     const int* __restrict__ bcur,
                                                     int* __restrict__ off2,
                                                     int* __restrict__ deg2){
    __shared__ int hist[RNODES2];
    __shared__ int pref[RNODES2];
    __shared__ int seg[BCAP];
    __shared__ int sums[256];
    int sg = blockIdx.x / RGS, rg = blockIdx.x % RGS;
    int tid = threadIdx.x;
    int cnt = bcur[sg*RGS + rg];
    if (cnt > BCAP) cnt = BCAP;
    size_t base = (size_t)(sg*RGS + rg)*BCAP;

    for (int i = tid; i < RNODES2; i += 256) hist[i] = 0;
    __syncthreads();
    for (int j = tid; j < cnt; j += 256)
        atomicAdd(&hist[bkt[base + j] >> 15], 1);
    __syncthreads();

    int lo = tid*3, hi = min(lo+3, RNODES2);
    int s = 0;
    for (int i = lo; i < hi; ++i) s += hist[i];
    sums[tid] = s; __syncthreads();
    for (int ofs = 1; ofs < 256; ofs <<= 1){
        int v = (tid >= ofs) ? sums[tid-ofs] : 0;
        __syncthreads();
        sums[tid] += v;
        __syncthreads();
    }
    int run = sums[tid] - s;
    int gnode = sg*NN + rg*RNODES2;
    for (int i = lo; i < hi; ++i){
        pref[i] = run;
        off2[gnode + i] = (int)base + run;
        deg2[gnode + i] = hist[i];
        run += hist[i];
    }
    __syncthreads();

    for (int j = tid; j < cnt; j += 256){
        int p = bkt[base + j];
        int slot = atomicAdd(&pref[p >> 15], 1);
        seg[slot] = p & 0x7FFF;
    }
    __syncthreads();

    for (int j = tid; j < cnt; j += 256) bkt[base + j] = seg[j];
}

// ---------------- x -> bf16 convert ----------------

__global__ __launch_bounds__(256) void convert_kernel(const float* __restrict__ x,
                                                      unsigned short* __restrict__ xb){
    int idx = blockIdx.x*256 + threadIdx.x;
    if (idx >= SG*NN*16) return;
    float4 v = ((const float4*)x)[idx];
    uint2 pk;
    pk.x = (unsigned)f2bf(v.x) | ((unsigned)f2bf(v.y) << 16);
    pk.y = (unsigned)f2bf(v.z) | ((unsigned)f2bf(v.w) << 16);
    ((uint2*)xb)[idx] = pk;
}

// ---------------- weight prep: all bf16, [col][k] layouts ----------------

__global__ __launch_bounds__(256) void wprep2_kernel(const float* __restrict__ W1l,
                                                     const float* __restrict__ W1r,
                                                     const float* __restrict__ W2l,
                                                     const float* __restrict__ W2r,
                                                     const float* __restrict__ Wih,
                                                     const float* __restrict__ Whh,
                                                     const float* __restrict__ bih,
                                                     const float* __restrict__ bhh,
                                                     unsigned short* __restrict__ WL1,
                                                     unsigned short* __restrict__ WL2,
                                                     unsigned short* __restrict__ Wt,
                                                     float* __restrict__ bc){
    int idx = blockIdx.x*256 + threadIdx.x;
    if (idx < 24576){
        int g = idx >> 13, rem = idx & 8191, col = rem >> 7, k = rem & 127;
        float v = (k < 64) ? W1l[((size_t)g*64 + k)*64 + col]
                           : W1r[((size_t)g*64 + (k-64))*64 + col];
        WL1[idx] = f2bf(v);
    } else if (idx < 49152){
        int t = idx - 24576;
        int g = t >> 13, rem = t & 8191, col = rem >> 7, k = rem & 127;
        float v = (k < 64) ? W2l[((size_t)g*64 + k)*64 + col]
                           : W2r[((size_t)g*64 + (k-64))*64 + col];
        WL2[t] = f2bf(v);
    } else if (idx < 81920){
        int t = idx - 49152;
        int col = t >> 7, k = t & 127;
        float v = (k < 64) ? Wih[col*64 + k] : Whh[col*64 + (k - 64)];
        Wt[t] = f2bf(v);
    } else if (idx < 82176){
        int t = idx - 81920;
        bc[t] = bih[t] + bhh[t];
    }
}

// ---------------- SAGE layer: barrier-free, per-wave slices; dual-row gather ----------------

#define WP 72

__global__ __launch_bounds__(256) void layer_kernel(const unsigned short* __restrict__ xb,
                                                    const int* __restrict__ off2,
                                                    const int* __restrict__ deg2,
                                                    const int* __restrict__ csr,
                                                    const unsigned short* __restrict__ WL,
                                                    const float* __restrict__ bias,
                                                    unsigned short* __restrict__ outb){
    __shared__ unsigned short sM[4][16*WP];  // mean slices
    __shared__ unsigned short sO[4][16*WP];  // out slices
    int tile = blockIdx.x, sg = blockIdx.y;
    int g = sg % G;
    int tid = threadIdx.x;
    int row0 = tile*64;
    const unsigned short* inb = xb + (size_t)sg*NN*D;

    int wave = tid >> 6, lane = tid & 63;
    int i0 = row0 + wave*16;

    // aggregation: 8 groups x 8 lanes; group owns rows (gp, 8+gp) jointly -> 2x loads in flight
    {
        int gp = lane >> 3, fl = lane & 7;
        int ii = min(i0 + (lane & 15), NN-1);
        int val = (lane < 16) ? off2[sg*NN + ii] : ((lane < 32) ? deg2[sg*NN + ii] : 0);
        int r0loc = gp, r1loc = 8 + gp;
        int a0  = __shfl(val, r0loc, 64);
        int dg0 = __shfl(val, 16 + r0loc, 64);
        int a1  = __shfl(val, r1loc, 64);
        int dg1 = __shfl(val, 16 + r1loc, 64);
        if (i0 + r0loc >= NN) dg0 = 0;
        if (i0 + r1loc >= NN) dg1 = 0;
        float acc0[8] = {0,0,0,0,0,0,0,0};
        float acc1[8] = {0,0,0,0,0,0,0,0};
        int mx = max(dg0, dg1);
        for (int base = 0; base < mx; base += 8){
            int my0 = 0, my1 = 0;
            if (base + fl < dg0) my0 = csr[a0 + base + fl];
            if (base + fl < dg1) my1 = csr[a1 + base + fl];
            #pragma unroll
            for (int j = 0; j < 8; ++j){
                int n0j = __shfl(my0, gp*8 + j, 64);
                int n1j = __shfl(my1, gp*8 + j, 64);
                if (base + j < dg0){
                    uint4 v = *(const uint4*)&inb[(size_t)n0j*D + fl*8];
                    acc0[0] += __uint_as_float(v.x << 16);
                    acc0[1] += __uint_as_float(v.x & 0xFFFF0000u);
                    acc0[2] += __uint_as_float(v.y << 16);
                    acc0[3] += __uint_as_float(v.y & 0xFFFF0000u);
                    acc0[4] += __uint_as_float(v.z << 16);
                    acc0[5] += __uint_as_float(v.z & 0xFFFF0000u);
                    acc0[6] += __uint_as_float(v.w << 16);
                    acc0[7] += __uint_as_float(v.w & 0xFFFF0000u);
                }
                if (base + j < dg1){
                    uint4 v = *(const uint4*)&inb[(size_t)n1j*D + fl*8];
                    acc1[0] += __uint_as_float(v.x << 16);
                    acc1[1] += __uint_as_float(v.x & 0xFFFF0000u);
                    acc1[2] += __uint_as_float(v.y << 16);
                    acc1[3] += __uint_as_float(v.y & 0xFFFF0000u);
                    acc1[4] += __uint_as_float(v.z << 16);
                    acc1[5] += __uint_as_float(v.z & 0xFFFF0000u);
                    acc1[6] += __uint_as_float(v.w << 16);
                    acc1[7] += __uint_as_float(v.w & 0xFFFF0000u);
                }
            }
        }
        float inv0 = (dg0 > 0) ? rcpf((float)dg0) : 0.0f;
        float inv1 = (dg1 > 0) ? rcpf((float)dg1) : 0.0f;
        uint4 pk;
        pk.x = (unsigned)f2bf(acc0[0]*inv0) | ((unsigned)f2bf(acc0[1]*inv0) << 16);
        pk.y = (unsigned)f2bf(acc0[2]*inv0) | ((unsigned)f2bf(acc0[3]*inv0) << 16);
        pk.z = (unsigned)f2bf(acc0[4]*inv0) | ((unsigned)f2bf(acc0[5]*inv0) << 16);
        pk.w = (unsigned)f2bf(acc0[6]*inv0) | ((unsigned)f2bf(acc0[7]*inv0) << 16);
        *(uint4*)&sM[wave][r0loc*WP + fl*8] = pk;
        pk.x = (unsigned)f2bf(acc1[0]*inv1) | ((unsigned)f2bf(acc1[1]*inv1) << 16);
        pk.y = (unsigned)f2bf(acc1[2]*inv1) | ((unsigned)f2bf(acc1[3]*inv1) << 16);
        pk.z = (unsigned)f2bf(acc1[4]*inv1) | ((unsigned)f2bf(acc1[5]*inv1) << 16);
        pk.w = (unsigned)f2bf(acc1[6]*inv1) | ((unsigned)f2bf(acc1[7]*inv1) << 16);
        *(uint4*)&sM[wave][r1loc*WP + fl*8] = pk;
    }
    // no barrier: consumers are this same wave (lgkmcnt ordering)

    int n0 = lane & 15, q = lane >> 4;
    const unsigned short* WLg = WL + (size_t)g*64*128;
    f32x4 accv[4];
    #pragma unroll
    for (int ct = 0; ct < 4; ++ct) accv[ct] = (f32x4){0.f,0.f,0.f,0.f};
    int irow = min(i0 + n0, NN-1);
    #pragma unroll
    for (int kc = 0; kc < 4; ++kc){
        bf16x8 af;
        if (kc < 2) af = *(const bf16x8*)&sM[wave][n0*WP + kc*32 + q*8];
        else        af = *(const bf16x8*)&inb[(size_t)irow*D + (kc-2)*32 + q*8];
        #pragma unroll
        for (int ct = 0; ct < 4; ++ct){
            bf16x8 bfr = *(const bf16x8*)&WLg[(ct*16 + n0)*128 + kc*32 + q*8];
            accv[ct] = __builtin_amdgcn_mfma_f32_16x16x32_bf16(af, bfr, accv[ct], 0, 0, 0);
        }
    }
    #pragma unroll
    for (int ct = 0; ct < 4; ++ct){
        float bv = bias[g*64 + ct*16 + n0];
        #pragma unroll
        for (int reg = 0; reg < 4; ++reg)
            sO[wave][(q*4+reg)*WP + ct*16 + n0] = f2bf(tanhf_fast(accv[ct][reg] + bv));
    }
    #pragma unroll
    for (int pass = 0; pass < 2; ++pass){
        int rloc = pass*8 + (lane >> 3), chunk = lane & 7;
        int i = i0 + rloc;
        if (i < NN){
            uint4 v = *(const uint4*)&sO[wave][rloc*WP + chunk*8];
            *(uint4*)&outb[((size_t)sg*NN + i)*D + chunk*8] = v;
        }
    }
}

// ---------------- LSTM: col-partitioned waves; Wt read once per block; 3 barriers ----------------
// Wave w owns gate-cols [16w,16w+16) for all 64 rows: ct = T*4 + w.
// a-frags: 4 row-tiles from global (x) / LDS (h). h exchanged via block LDS.

__global__ __launch_bounds__(256) void lstm_kernel(const unsigned short* __restrict__ h2b,
                                                   const unsigned short* __restrict__ Wt,
                                                   const float* __restrict__ bc,
                                                   float* __restrict__ out){
    __shared__ unsigned short sH[64*WP];  // 9.2 KB, whole block's h
    int tid = threadIdx.x;
    int b0 = blockIdx.x * 64;
    int wave = tid >> 6, lane = tid & 63;
    int n0 = lane & 15, q = lane >> 4;
    int jcol = wave*16 + n0;              // output col j in [0,64)

    float bb[4];
    #pragma unroll
    for (int T = 0; T < 4; ++T) bb[T] = bc[T*64 + jcol];

    float c[4][4];  // [rt][reg]
    #pragma unroll
    for (int rt = 0; rt < 4; ++rt)
        #pragma unroll
        for (int reg = 0; reg < 4; ++reg) c[rt][reg] = 0.0f;

    // lane's a-row (per row-tile) global coords, fixed across t
    int s_[4], n_[4];
    #pragma unroll
    for (int rt = 0; rt < 4; ++rt){
        int b = b0 + rt*16 + n0;
        s_[rt] = b / NN; n_[rt] = b - s_[rt]*NN;
    }

    #pragma unroll
    for (int t = 0; t < G; ++t){
        f32x4 accv[4][4];  // [rt][T]
        #pragma unroll
        for (int rt = 0; rt < 4; ++rt)
            #pragma unroll
            for (int T = 0; T < 4; ++T) accv[rt][T] = (f32x4){0.f,0.f,0.f,0.f};

        int nkc = (t == 0) ? 2 : 4;
        #pragma unroll
        for (int kc = 0; kc < 4; ++kc){
            if (kc >= nkc) break;
            bf16x8 af[4];
            #pragma unroll
            for (int rt = 0; rt < 4; ++rt){
                if (kc < 2) af[rt] = *(const bf16x8*)&h2b[((size_t)(s_[rt]*G + t)*NN + n_[rt])*D + kc*32 + q*8];
                else        af[rt] = *(const bf16x8*)&sH[(rt*16 + n0)*WP + (kc-2)*32 + q*8];
            }
            #pragma unroll
            for (int T = 0; T < 4; ++T){
                int ct = T*4 + wave;
                bf16x8 bfr = *(const bf16x8*)&Wt[(ct*16 + n0)*128 + kc*32 + q*8];
                #pragma unroll
                for (int rt = 0; rt < 4; ++rt)
                    accv[rt][T] = __builtin_amdgcn_mfma_f32_16x16x32_bf16(af[rt], bfr, accv[rt][T], 0, 0, 0);
            }
        }
        if (t > 0) __syncthreads();   // WAR: all sH reads done before overwrite

        #pragma unroll
        for (int rt = 0; rt < 4; ++rt){
            #pragma unroll
            for (int reg = 0; reg < 4; ++reg){
                float ig = sigmf(accv[rt][0][reg] + bb[0]);
                float fg = sigmf(accv[rt][1][reg] + bb[1]);
                float gg = tanhf_fast(accv[rt][2][reg] + bb[2]);
                float og = sigmf(accv[rt][3][reg] + bb[3]);
                float cn = fg*c[rt][reg] + ig*gg;
                c[rt][reg] = cn;
                float hv = og * tanhf_fast(cn);
                int row = rt*16 + q*4 + reg;
                if (t < G-1) sH[row*WP + jcol] = f2bf(hv);
                else         out[(size_t)(b0 + row)*D + jcol] = hv;
            }
        }
        if (t < G-1) __syncthreads(); // RAW: h visible before next t's reads
    }
}

// ---------------- host ----------------

extern "C" void kernel_launch(void* const* d_in, const int* in_sizes, int n_in,
                              void* d_out, int out_size, void* d_ws, size_t ws_size,
                              hipStream_t stream) {
    const float* x   = (const float*)d_in[0];
    const int*   ei  = (const int*)  d_in[1];
    const float* W1l = (const float*)d_in[2];
    const float* W1r = (const float*)d_in[3];
    const float* b1  = (const float*)d_in[4];
    const float* W2l = (const float*)d_in[5];
    const float* W2r = (const float*)d_in[6];
    const float* b2  = (const float*)d_in[7];
    const float* Wih = (const float*)d_in[8];
    const float* Whh = (const float*)d_in[9];
    const float* bih = (const float*)d_in[10];
    const float* bhh = (const float*)d_in[11];
    float* out = (float*)d_out;

    char* ws = (char*)d_ws;
    size_t cur = 0;
    auto alloc = [&](size_t bytes)->void*{
        cur = (cur + 255) & ~(size_t)255;
        void* p = ws + cur; cur += bytes; return p;
    };
    int*   bkt  = (int*)alloc((size_t)SG*RGS*BCAP*4);   // buckets, then CSR in place
    int*   bcur = (int*)alloc((size_t)SG*RGS*4);
    int*   off2 = (int*)alloc((size_t)SG*NN*4);
    int*   deg2 = (int*)alloc((size_t)SG*NN*4);
    unsigned short* xb  = (unsigned short*)alloc((size_t)SG*NN*D*2);
    unsigned short* h1b = (unsigned short*)alloc((size_t)SG*NN*D*2);
    unsigned short* h2b = (unsigned short*)alloc((size_t)SG*NN*D*2);
    unsigned short* WL1 = (unsigned short*)alloc((size_t)G*64*128*2);
    unsigned short* WL2 = (unsigned short*)alloc((size_t)G*64*128*2);
    unsigned short* Wt  = (unsigned short*)alloc((size_t)256*128*2);
    float* bc   = (float*)alloc((size_t)256*4);
    (void)ws_size; (void)in_sizes; (void)n_in; (void)out_size;

    (void)hipMemsetAsync(bcur, 0, (size_t)SG*RGS*4, stream);

    convert_kernel<<<(SG*NN*16 + 255)/256, 256, 0, stream>>>(x, xb);
    binA_kernel  <<<dim3(CHUNKA, SG), 256, 0, stream>>>(ei, bcur, bkt);
    buildB_kernel<<<SG*RGS, 256, 0, stream>>>(bkt, bcur, off2, deg2);
    wprep2_kernel<<<321, 256, 0, stream>>>(W1l, W1r, W2l, W2r, Wih, Whh, bih, bhh,
                                           WL1, WL2, Wt, bc);

    dim3 lgrid((NN + 63)/64, SG);
    layer_kernel<<<lgrid, 256, 0, stream>>>(xb,  off2, deg2, bkt, WL1, b1, h1b);
    layer_kernel<<<lgrid, 256, 0, stream>>>(h1b, off2, deg2, bkt, WL2, b2, h2b);

    lstm_kernel <<<(S*NN)/64, 256, 0, stream>>>(h2b, Wt, bc, out);
}

// Round 11
// 393.920 us; speedup vs baseline: 2.8210x; 1.0928x over previous
//
#include <hip/hip_runtime.h>
#include <math.h>

#define S 4
#define G 3
#define NN 20000
#define EE 320000
#define D 64
#define SG (S*G)

#define RGS 32           // dst-ranges per graph
#define RNODES2 625      // NN / RGS
#define BCAP 12000       // bucket capacity per (sg,range); mean 10000
#define CHUNKA 100       // edge chunks per sg in binA; 320000/100 = 3200 edges/block

// layer task swizzle: 12 sg x 314 tiles = 3768 = 8 XCD x 471 tasks
#define LTILES 314
#define LTASKS (12*LTILES)
#define LPERX  (LTASKS/8)   // 471

static __device__ __forceinline__ float rcpf(float x){ return __builtin_amdgcn_rcpf(x); }
static __device__ __forceinline__ float sigmf(float x){ return rcpf(1.0f + __expf(-x)); }
// fast tanh: 1 - 2/(e^{2x}+1), v_rcp for the divide; saturates correctly
static __device__ __forceinline__ float tanhf_fast(float x){
    float t = __expf(2.0f*x);
    return 1.0f - 2.0f*rcpf(t + 1.0f);
}

// float -> bf16 bits, round-nearest-even
static __device__ __forceinline__ unsigned short f2bf(float f){
    union { float f; unsigned u; } v; v.f = f;
    unsigned r = v.u + 0x7FFF + ((v.u >> 16) & 1);
    return (unsigned short)(r >> 16);
}

typedef short bf16x8 __attribute__((ext_vector_type(8)));
typedef float f32x4  __attribute__((ext_vector_type(4)));

// ---------------- Phase A: bin edges into 32 dst-range buckets, packed (dstLoc<<15)|src ----------------

__global__ __launch_bounds__(256) void binA_kernel(const int* __restrict__ ei,
                                                   int* __restrict__ bcur,
                                                   int* __restrict__ bkt){
    __shared__ int wcnt[4*RGS];
    __shared__ int wb[4*RGS];
    int chunk = blockIdx.x, sg = blockIdx.y;
    int tid = threadIdx.x, w = tid >> 6;
    const int* srcp = ei + (size_t)(sg*2 + 0)*EE;
    const int* dstp = ei + (size_t)(sg*2 + 1)*EE;
    const int EPC = EE/CHUNKA;               // 3200
    int start = chunk*EPC, end = start + EPC;

    for (int it = 0; it < (EPC + 1023)/1024; ++it){
        if (tid < 4*RGS) wcnt[tid] = 0;
        __syncthreads();
        int e = start + it*1024 + tid*4;
        bool valid = e < end;
        int d_[4], s_[4], r_[4], dl_[4], rk_[4];
        if (valid){
            int4 d4 = *(const int4*)&dstp[e];
            int4 s4 = *(const int4*)&srcp[e];
            d_[0]=d4.x; d_[1]=d4.y; d_[2]=d4.z; d_[3]=d4.w;
            s_[0]=s4.x; s_[1]=s4.y; s_[2]=s4.z; s_[3]=s4.w;
            #pragma unroll
            for (int j = 0; j < 4; ++j){
                int r = d_[j] / RNODES2;
                r_[j]  = r;
                dl_[j] = d_[j] - r*RNODES2;
                rk_[j] = atomicAdd(&wcnt[w*RGS + r], 1);
            }
        }
        __syncthreads();
        if (tid < RGS){
            int c0 = wcnt[0*RGS+tid], c1 = wcnt[1*RGS+tid];
            int c2 = wcnt[2*RGS+tid], c3 = wcnt[3*RGS+tid];
            int tot = c0+c1+c2+c3;
            int gb = 0;
            if (tot > 0) gb = atomicAdd(&bcur[sg*RGS + tid], tot);
            wb[0*RGS+tid] = gb;
            wb[1*RGS+tid] = gb + c0;
            wb[2*RGS+tid] = gb + c0 + c1;
            wb[3*RGS+tid] = gb + c0 + c1 + c2;
        }
        __syncthreads();
        if (valid){
            #pragma unroll
            for (int j = 0; j < 4; ++j){
                int pos = wb[w*RGS + r_[j]] + rk_[j];
                if (pos < BCAP)
                    bkt[(size_t)(sg*RGS + r_[j])*BCAP + pos] = (dl_[j] << 15) | s_[j];
            }
        }
    }
}

// ---------------- Phase B: per (sg,range): hist -> scan -> CSR segment -> in-place dump ----------------

__global__ __launch_bounds__(256) void buildB_kernel(int* __restrict__ bkt,
                                                     const int* __restrict__ bcur,
                                                     int* __restrict__ off2,
                                                     int* __restrict__ deg2){
    __shared__ int hist[RNODES2];
    __shared__ int pref[RNODES2];
    __shared__ int seg[BCAP];
    __shared__ int sums[256];
    int sg = blockIdx.x / RGS, rg = blockIdx.x % RGS;
    int tid = threadIdx.x;
    int cnt = bcur[sg*RGS + rg];
    if (cnt > BCAP) cnt = BCAP;
    size_t base = (size_t)(sg*RGS + rg)*BCAP;

    for (int i = tid; i < RNODES2; i += 256) hist[i] = 0;
    __syncthreads();
    for (int j = tid; j < cnt; j += 256)
        atomicAdd(&hist[bkt[base + j] >> 15], 1);
    __syncthreads();

    int lo = tid*3, hi = min(lo+3, RNODES2);
    int s = 0;
    for (int i = lo; i < hi; ++i) s += hist[i];
    sums[tid] = s; __syncthreads();
    for (int ofs = 1; ofs < 256; ofs <<= 1){
        int v = (tid >= ofs) ? sums[tid-ofs] : 0;
        __syncthreads();
        sums[tid] += v;
        __syncthreads();
    }
    int run = sums[tid] - s;
    int gnode = sg*NN + rg*RNODES2;
    for (int i = lo; i < hi; ++i){
        pref[i] = run;
        off2[gnode + i] = (int)base + run;
        deg2[gnode + i] = hist[i];
        run += hist[i];
    }
    __syncthreads();

    for (int j = tid; j < cnt; j += 256){
        int p = bkt[base + j];
        int slot = atomicAdd(&pref[p >> 15], 1);
        seg[slot] = p & 0x7FFF;
    }
    __syncthreads();

    for (int j = tid; j < cnt; j += 256) bkt[base + j] = seg[j];
}

// ---------------- x -> bf16 convert ----------------

__global__ __launch_bounds__(256) void convert_kernel(const float* __restrict__ x,
                                                      unsigned short* __restrict__ xb){
    int idx = blockIdx.x*256 + threadIdx.x;
    if (idx >= SG*NN*16) return;
    float4 v = ((const float4*)x)[idx];
    uint2 pk;
    pk.x = (unsigned)f2bf(v.x) | ((unsigned)f2bf(v.y) << 16);
    pk.y = (unsigned)f2bf(v.z) | ((unsigned)f2bf(v.w) << 16);
    ((uint2*)xb)[idx] = pk;
}

// ---------------- weight prep: all bf16, [col][k] layouts ----------------

__global__ __launch_bounds__(256) void wprep2_kernel(const float* __restrict__ W1l,
                                                     const float* __restrict__ W1r,
                                                     const float* __restrict__ W2l,
                                                     const float* __restrict__ W2r,
                                                     const float* __restrict__ Wih,
                                                     const float* __restrict__ Whh,
                                                     const float* __restrict__ bih,
                                                     const float* __restrict__ bhh,
                                                     unsigned short* __restrict__ WL1,
                                                     unsigned short* __restrict__ WL2,
                                                     unsigned short* __restrict__ Wt,
                                                     float* __restrict__ bc){
    int idx = blockIdx.x*256 + threadIdx.x;
    if (idx < 24576){
        int g = idx >> 13, rem = idx & 8191, col = rem >> 7, k = rem & 127;
        float v = (k < 64) ? W1l[((size_t)g*64 + k)*64 + col]
                           : W1r[((size_t)g*64 + (k-64))*64 + col];
        WL1[idx] = f2bf(v);
    } else if (idx < 49152){
        int t = idx - 24576;
        int g = t >> 13, rem = t & 8191, col = rem >> 7, k = rem & 127;
        float v = (k < 64) ? W2l[((size_t)g*64 + k)*64 + col]
                           : W2r[((size_t)g*64 + (k-64))*64 + col];
        WL2[t] = f2bf(v);
    } else if (idx < 81920){
        int t = idx - 49152;
        int col = t >> 7, k = t & 127;
        float v = (k < 64) ? Wih[col*64 + k] : Whh[col*64 + (k - 64)];
        Wt[t] = f2bf(v);
    } else if (idx < 82176){
        int t = idx - 81920;
        bc[t] = bih[t] + bhh[t];
    }
}

// ---------------- SAGE layer: barrier-free, per-wave slices; dual-row gather;
// XCD-affinity task swizzle: block L -> XCD L%8 -> contiguous sg-major task range ----------------

#define WP 72

__global__ __launch_bounds__(256) void layer_kernel(const unsigned short* __restrict__ xb,
                                                    const int* __restrict__ off2,
                                                    const int* __restrict__ deg2,
                                                    const int* __restrict__ csr,
                                                    const unsigned short* __restrict__ WL,
                                                    const float* __restrict__ bias,
                                                    unsigned short* __restrict__ outb){
    __shared__ unsigned short sM[4][16*WP];  // mean slices
    __shared__ unsigned short sO[4][16*WP];  // out slices
    // XCD-affinity swizzle: dispatch round-robins blocks over 8 XCDs (L%8).
    // Give XCD x the contiguous sg-major range [x*LPERX, (x+1)*LPERX).
    int L = blockIdx.x;
    int xcd = L & 7, k = L >> 3;
    int task = xcd*LPERX + k;
    int sg = task / LTILES;
    int tile = task - sg*LTILES;
    if (tile >= (NN + 63)/64) return;   // pad task (no barriers in kernel -> safe)
    int g = sg % G;
    int tid = threadIdx.x;
    int row0 = tile*64;
    const unsigned short* inb = xb + (size_t)sg*NN*D;

    int wave = tid >> 6, lane = tid & 63;
    int i0 = row0 + wave*16;

    // aggregation: 8 groups x 8 lanes; group owns rows (gp, 8+gp) jointly -> 2x loads in flight
    {
        int gp = lane >> 3, fl = lane & 7;
        int ii = min(i0 + (lane & 15), NN-1);
        int val = (lane < 16) ? off2[sg*NN + ii] : ((lane < 32) ? deg2[sg*NN + ii] : 0);
        int r0loc = gp, r1loc = 8 + gp;
        int a0  = __shfl(val, r0loc, 64);
        int dg0 = __shfl(val, 16 + r0loc, 64);
        int a1  = __shfl(val, r1loc, 64);
        int dg1 = __shfl(val, 16 + r1loc, 64);
        if (i0 + r0loc >= NN) dg0 = 0;
        if (i0 + r1loc >= NN) dg1 = 0;
        float acc0[8] = {0,0,0,0,0,0,0,0};
        float acc1[8] = {0,0,0,0,0,0,0,0};
        int mx = max(dg0, dg1);
        for (int base = 0; base < mx; base += 8){
            int my0 = 0, my1 = 0;
            if (base + fl < dg0) my0 = csr[a0 + base + fl];
            if (base + fl < dg1) my1 = csr[a1 + base + fl];
            #pragma unroll
            for (int j = 0; j < 8; ++j){
                int n0j = __shfl(my0, gp*8 + j, 64);
                int n1j = __shfl(my1, gp*8 + j, 64);
                if (base + j < dg0){
                    uint4 v = *(const uint4*)&inb[(size_t)n0j*D + fl*8];
                    acc0[0] += __uint_as_float(v.x << 16);
                    acc0[1] += __uint_as_float(v.x & 0xFFFF0000u);
                    acc0[2] += __uint_as_float(v.y << 16);
                    acc0[3] += __uint_as_float(v.y & 0xFFFF0000u);
                    acc0[4] += __uint_as_float(v.z << 16);
                    acc0[5] += __uint_as_float(v.z & 0xFFFF0000u);
                    acc0[6] += __uint_as_float(v.w << 16);
                    acc0[7] += __uint_as_float(v.w & 0xFFFF0000u);
                }
                if (base + j < dg1){
                    uint4 v = *(const uint4*)&inb[(size_t)n1j*D + fl*8];
                    acc1[0] += __uint_as_float(v.x << 16);
                    acc1[1] += __uint_as_float(v.x & 0xFFFF0000u);
                    acc1[2] += __uint_as_float(v.y << 16);
                    acc1[3] += __uint_as_float(v.y & 0xFFFF0000u);
                    acc1[4] += __uint_as_float(v.z << 16);
                    acc1[5] += __uint_as_float(v.z & 0xFFFF0000u);
                    acc1[6] += __uint_as_float(v.w << 16);
                    acc1[7] += __uint_as_float(v.w & 0xFFFF0000u);
                }
            }
        }
        float inv0 = (dg0 > 0) ? rcpf((float)dg0) : 0.0f;
        float inv1 = (dg1 > 0) ? rcpf((float)dg1) : 0.0f;
        uint4 pk;
        pk.x = (unsigned)f2bf(acc0[0]*inv0) | ((unsigned)f2bf(acc0[1]*inv0) << 16);
        pk.y = (unsigned)f2bf(acc0[2]*inv0) | ((unsigned)f2bf(acc0[3]*inv0) << 16);
        pk.z = (unsigned)f2bf(acc0[4]*inv0) | ((unsigned)f2bf(acc0[5]*inv0) << 16);
        pk.w = (unsigned)f2bf(acc0[6]*inv0) | ((unsigned)f2bf(acc0[7]*inv0) << 16);
        *(uint4*)&sM[wave][r0loc*WP + fl*8] = pk;
        pk.x = (unsigned)f2bf(acc1[0]*inv1) | ((unsigned)f2bf(acc1[1]*inv1) << 16);
        pk.y = (unsigned)f2bf(acc1[2]*inv1) | ((unsigned)f2bf(acc1[3]*inv1) << 16);
        pk.z = (unsigned)f2bf(acc1[4]*inv1) | ((unsigned)f2bf(acc1[5]*inv1) << 16);
        pk.w = (unsigned)f2bf(acc1[6]*inv1) | ((unsigned)f2bf(acc1[7]*inv1) << 16);
        *(uint4*)&sM[wave][r1loc*WP + fl*8] = pk;
    }
    // no barrier: consumers are this same wave (lgkmcnt ordering)

    int n0 = lane & 15, q = lane >> 4;
    const unsigned short* WLg = WL + (size_t)g*64*128;
    f32x4 accv[4];
    #pragma unroll
    for (int ct = 0; ct < 4; ++ct) accv[ct] = (f32x4){0.f,0.f,0.f,0.f};
    int irow = min(i0 + n0, NN-1);
    #pragma unroll
    for (int kc = 0; kc < 4; ++kc){
        bf16x8 af;
        if (kc < 2) af = *(const bf16x8*)&sM[wave][n0*WP + kc*32 + q*8];
        else        af = *(const bf16x8*)&inb[(size_t)irow*D + (kc-2)*32 + q*8];
        #pragma unroll
        for (int ct = 0; ct < 4; ++ct){
            bf16x8 bfr = *(const bf16x8*)&WLg[(ct*16 + n0)*128 + kc*32 + q*8];
            accv[ct] = __builtin_amdgcn_mfma_f32_16x16x32_bf16(af, bfr, accv[ct], 0, 0, 0);
        }
    }
    #pragma unroll
    for (int ct = 0; ct < 4; ++ct){
        float bv = bias[g*64 + ct*16 + n0];
        #pragma unroll
        for (int reg = 0; reg < 4; ++reg)
            sO[wave][(q*4+reg)*WP + ct*16 + n0] = f2bf(tanhf_fast(accv[ct][reg] + bv));
    }
    #pragma unroll
    for (int pass = 0; pass < 2; ++pass){
        int rloc = pass*8 + (lane >> 3), chunk = lane & 7;
        int i = i0 + rloc;
        if (i < NN){
            uint4 v = *(const uint4*)&sO[wave][rloc*WP + chunk*8];
            *(uint4*)&outb[((size_t)sg*NN + i)*D + chunk*8] = v;
        }
    }
}

// ---------------- LSTM: col-partitioned waves; Wt read once per block; 3 barriers ----------------

__global__ __launch_bounds__(256) void lstm_kernel(const unsigned short* __restrict__ h2b,
                                                   const unsigned short* __restrict__ Wt,
                                                   const float* __restrict__ bc,
                                                   float* __restrict__ out){
    __shared__ unsigned short sH[64*WP];  // 9.2 KB, whole block's h
    int tid = threadIdx.x;
    int b0 = blockIdx.x * 64;
    int wave = tid >> 6, lane = tid & 63;
    int n0 = lane & 15, q = lane >> 4;
    int jcol = wave*16 + n0;              // output col j in [0,64)

    float bb[4];
    #pragma unroll
    for (int T = 0; T < 4; ++T) bb[T] = bc[T*64 + jcol];

    float c[4][4];  // [rt][reg]
    #pragma unroll
    for (int rt = 0; rt < 4; ++rt)
        #pragma unroll
        for (int reg = 0; reg < 4; ++reg) c[rt][reg] = 0.0f;

    int s_[4], n_[4];
    #pragma unroll
    for (int rt = 0; rt < 4; ++rt){
        int b = b0 + rt*16 + n0;
        s_[rt] = b / NN; n_[rt] = b - s_[rt]*NN;
    }

    #pragma unroll
    for (int t = 0; t < G; ++t){
        f32x4 accv[4][4];  // [rt][T]
        #pragma unroll
        for (int rt = 0; rt < 4; ++rt)
            #pragma unroll
            for (int T = 0; T < 4; ++T) accv[rt][T] = (f32x4){0.f,0.f,0.f,0.f};

        int nkc = (t == 0) ? 2 : 4;
        #pragma unroll
        for (int kc = 0; kc < 4; ++kc){
            if (kc >= nkc) break;
            bf16x8 af[4];
            #pragma unroll
            for (int rt = 0; rt < 4; ++rt){
                if (kc < 2) af[rt] = *(const bf16x8*)&h2b[((size_t)(s_[rt]*G + t)*NN + n_[rt])*D + kc*32 + q*8];
                else        af[rt] = *(const bf16x8*)&sH[(rt*16 + n0)*WP + (kc-2)*32 + q*8];
            }
            #pragma unroll
            for (int T = 0; T < 4; ++T){
                int ct = T*4 + wave;
                bf16x8 bfr = *(const bf16x8*)&Wt[(ct*16 + n0)*128 + kc*32 + q*8];
                #pragma unroll
                for (int rt = 0; rt < 4; ++rt)
                    accv[rt][T] = __builtin_amdgcn_mfma_f32_16x16x32_bf16(af[rt], bfr, accv[rt][T], 0, 0, 0);
            }
        }
        if (t > 0) __syncthreads();   // WAR: all sH reads done before overwrite

        #pragma unroll
        for (int rt = 0; rt < 4; ++rt){
            #pragma unroll
            for (int reg = 0; reg < 4; ++reg){
                float ig = sigmf(accv[rt][0][reg] + bb[0]);
                float fg = sigmf(accv[rt][1][reg] + bb[1]);
                float gg = tanhf_fast(accv[rt][2][reg] + bb[2]);
                float og = sigmf(accv[rt][3][reg] + bb[3]);
                float cn = fg*c[rt][reg] + ig*gg;
                c[rt][reg] = cn;
                float hv = og * tanhf_fast(cn);
                int row = rt*16 + q*4 + reg;
                if (t < G-1) sH[row*WP + jcol] = f2bf(hv);
                else         out[(size_t)(b0 + row)*D + jcol] = hv;
            }
        }
        if (t < G-1) __syncthreads(); // RAW: h visible before next t's reads
    }
}

// ---------------- host ----------------

extern "C" void kernel_launch(void* const* d_in, const int* in_sizes, int n_in,
                              void* d_out, int out_size, void* d_ws, size_t ws_size,
                              hipStream_t stream) {
    const float* x   = (const float*)d_in[0];
    const int*   ei  = (const int*)  d_in[1];
    const float* W1l = (const float*)d_in[2];
    const float* W1r = (const float*)d_in[3];
    const float* b1  = (const float*)d_in[4];
    const float* W2l = (const float*)d_in[5];
    const float* W2r = (const float*)d_in[6];
    const float* b2  = (const float*)d_in[7];
    const float* Wih = (const float*)d_in[8];
    const float* Whh = (const float*)d_in[9];
    const float* bih = (const float*)d_in[10];
    const float* bhh = (const float*)d_in[11];
    float* out = (float*)d_out;

    char* ws = (char*)d_ws;
    size_t cur = 0;
    auto alloc = [&](size_t bytes)->void*{
        cur = (cur + 255) & ~(size_t)255;
        void* p = ws + cur; cur += bytes; return p;
    };
    int*   bkt  = (int*)alloc((size_t)SG*RGS*BCAP*4);   // buckets, then CSR in place
    int*   bcur = (int*)alloc((size_t)SG*RGS*4);
    int*   off2 = (int*)alloc((size_t)SG*NN*4);
    int*   deg2 = (int*)alloc((size_t)SG*NN*4);
    unsigned short* xb  = (unsigned short*)alloc((size_t)SG*NN*D*2);
    unsigned short* h1b = (unsigned short*)alloc((size_t)SG*NN*D*2);
    unsigned short* h2b = (unsigned short*)alloc((size_t)SG*NN*D*2);
    unsigned short* WL1 = (unsigned short*)alloc((size_t)G*64*128*2);
    unsigned short* WL2 = (unsigned short*)alloc((size_t)G*64*128*2);
    unsigned short* Wt  = (unsigned short*)alloc((size_t)256*128*2);
    float* bc   = (float*)alloc((size_t)256*4);
    (void)ws_size; (void)in_sizes; (void)n_in; (void)out_size;

    (void)hipMemsetAsync(bcur, 0, (size_t)SG*RGS*4, stream);

    convert_kernel<<<(SG*NN*16 + 255)/256, 256, 0, stream>>>(x, xb);
    binA_kernel  <<<dim3(CHUNKA, SG), 256, 0, stream>>>(ei, bcur, bkt);
    buildB_kernel<<<SG*RGS, 256, 0, stream>>>(bkt, bcur, off2, deg2);
    wprep2_kernel<<<321, 256, 0, stream>>>(W1l, W1r, W2l, W2r, Wih, Whh, bih, bhh,
                                           WL1, WL2, Wt, bc);

    layer_kernel<<<LTASKS, 256, 0, stream>>>(xb,  off2, deg2, bkt, WL1, b1, h1b);
    layer_kernel<<<LTASKS, 256, 0, stream>>>(h1b, off2, deg2, bkt, WL2, b2, h2b);

    lstm_kernel <<<(S*NN)/64, 256, 0, stream>>>(h2b, Wt, bc, out);
}

// Round 12
// 372.379 us; speedup vs baseline: 2.9841x; 1.0578x over previous
//
#include <hip/hip_runtime.h>
#include <math.h>

#define S 4
#define G 3
#define NN 20000
#define EE 320000
#define D 64
#define SG (S*G)

#define RGS 32           // dst-ranges per graph
#define RNODES2 625      // NN / RGS
#define BCAP 12000       // bucket capacity per (sg,range); mean 10000
#define CHUNKA 100       // edge chunks per sg in binA; 320000/100 = 3200 edges/block

// layer task swizzle: 12 sg x 314 tiles = 3768 = 8 XCD x 471 tasks
#define LTILES 314
#define LTASKS (12*LTILES)
#define LPERX  (LTASKS/8)   // 471

static __device__ __forceinline__ float rcpf(float x){ return __builtin_amdgcn_rcpf(x); }
static __device__ __forceinline__ float sigmf(float x){ return rcpf(1.0f + __expf(-x)); }
// fast tanh: 1 - 2/(e^{2x}+1), v_rcp for the divide; saturates correctly
static __device__ __forceinline__ float tanhf_fast(float x){
    float t = __expf(2.0f*x);
    return 1.0f - 2.0f*rcpf(t + 1.0f);
}

// float -> bf16 bits, round-nearest-even
static __device__ __forceinline__ unsigned short f2bf(float f){
    union { float f; unsigned u; } v; v.f = f;
    unsigned r = v.u + 0x7FFF + ((v.u >> 16) & 1);
    return (unsigned short)(r >> 16);
}

typedef short bf16x8 __attribute__((ext_vector_type(8)));
typedef float f32x4  __attribute__((ext_vector_type(4)));

// ---------------- Phase A: bin edges into 32 dst-range buckets, packed (dstLoc<<15)|src ----------------

__global__ __launch_bounds__(256) void binA_kernel(const int* __restrict__ ei,
                                                   int* __restrict__ bcur,
                                                   int* __restrict__ bkt){
    __shared__ int wcnt[4*RGS];
    __shared__ int wb[4*RGS];
    int chunk = blockIdx.x, sg = blockIdx.y;
    int tid = threadIdx.x, w = tid >> 6;
    const int* srcp = ei + (size_t)(sg*2 + 0)*EE;
    const int* dstp = ei + (size_t)(sg*2 + 1)*EE;
    const int EPC = EE/CHUNKA;               // 3200
    int start = chunk*EPC, end = start + EPC;

    for (int it = 0; it < (EPC + 1023)/1024; ++it){
        if (tid < 4*RGS) wcnt[tid] = 0;
        __syncthreads();
        int e = start + it*1024 + tid*4;
        bool valid = e < end;
        int d_[4], s_[4], r_[4], dl_[4], rk_[4];
        if (valid){
            int4 d4 = *(const int4*)&dstp[e];
            int4 s4 = *(const int4*)&srcp[e];
            d_[0]=d4.x; d_[1]=d4.y; d_[2]=d4.z; d_[3]=d4.w;
            s_[0]=s4.x; s_[1]=s4.y; s_[2]=s4.z; s_[3]=s4.w;
            #pragma unroll
            for (int j = 0; j < 4; ++j){
                int r = d_[j] / RNODES2;
                r_[j]  = r;
                dl_[j] = d_[j] - r*RNODES2;
                rk_[j] = atomicAdd(&wcnt[w*RGS + r], 1);
            }
        }
        __syncthreads();
        if (tid < RGS){
            int c0 = wcnt[0*RGS+tid], c1 = wcnt[1*RGS+tid];
            int c2 = wcnt[2*RGS+tid], c3 = wcnt[3*RGS+tid];
            int tot = c0+c1+c2+c3;
            int gb = 0;
            if (tot > 0) gb = atomicAdd(&bcur[sg*RGS + tid], tot);
            wb[0*RGS+tid] = gb;
            wb[1*RGS+tid] = gb + c0;
            wb[2*RGS+tid] = gb + c0 + c1;
            wb[3*RGS+tid] = gb + c0 + c1 + c2;
        }
        __syncthreads();
        if (valid){
            #pragma unroll
            for (int j = 0; j < 4; ++j){
                int pos = wb[w*RGS + r_[j]] + rk_[j];
                if (pos < BCAP)
                    bkt[(size_t)(sg*RGS + r_[j])*BCAP + pos] = (dl_[j] << 15) | s_[j];
            }
        }
    }
}

// ---------------- Phase B: per (sg,range): hist -> scan -> CSR segment -> in-place dump ----------------

__global__ __launch_bounds__(256) void buildB_kernel(int* __restrict__ bkt,
                                                     const int* __restrict__ bcur,
                                                     int* __restrict__ off2,
                                                     int* __restrict__ deg2){
    __shared__ int hist[RNODES2];
    __shared__ int pref[RNODES2];
    __shared__ int seg[BCAP];
    __shared__ int sums[256];
    int sg = blockIdx.x / RGS, rg = blockIdx.x % RGS;
    int tid = threadIdx.x;
    int cnt = bcur[sg*RGS + rg];
    if (cnt > BCAP) cnt = BCAP;
    size_t base = (size_t)(sg*RGS + rg)*BCAP;

    for (int i = tid; i < RNODES2; i += 256) hist[i] = 0;
    __syncthreads();
    for (int j = tid; j < cnt; j += 256)
        atomicAdd(&hist[bkt[base + j] >> 15], 1);
    __syncthreads();

    int lo = tid*3, hi = min(lo+3, RNODES2);
    int s = 0;
    for (int i = lo; i < hi; ++i) s += hist[i];
    sums[tid] = s; __syncthreads();
    for (int ofs = 1; ofs < 256; ofs <<= 1){
        int v = (tid >= ofs) ? sums[tid-ofs] : 0;
        __syncthreads();
        sums[tid] += v;
        __syncthreads();
    }
    int run = sums[tid] - s;
    int gnode = sg*NN + rg*RNODES2;
    for (int i = lo; i < hi; ++i){
        pref[i] = run;
        off2[gnode + i] = (int)base + run;
        deg2[gnode + i] = hist[i];
        run += hist[i];
    }
    __syncthreads();

    for (int j = tid; j < cnt; j += 256){
        int p = bkt[base + j];
        int slot = atomicAdd(&pref[p >> 15], 1);
        seg[slot] = p & 0x7FFF;
    }
    __syncthreads();

    for (int j = tid; j < cnt; j += 256) bkt[base + j] = seg[j];
}

// ---------------- x -> bf16 convert ----------------

__global__ __launch_bounds__(256) void convert_kernel(const float* __restrict__ x,
                                                      unsigned short* __restrict__ xb){
    int idx = blockIdx.x*256 + threadIdx.x;
    if (idx >= SG*NN*16) return;
    float4 v = ((const float4*)x)[idx];
    uint2 pk;
    pk.x = (unsigned)f2bf(v.x) | ((unsigned)f2bf(v.y) << 16);
    pk.y = (unsigned)f2bf(v.z) | ((unsigned)f2bf(v.w) << 16);
    ((uint2*)xb)[idx] = pk;
}

// ---------------- weight prep: all bf16, [col][k] layouts ----------------

__global__ __launch_bounds__(256) void wprep2_kernel(const float* __restrict__ W1l,
                                                     const float* __restrict__ W1r,
                                                     const float* __restrict__ W2l,
                                                     const float* __restrict__ W2r,
                                                     const float* __restrict__ Wih,
                                                     const float* __restrict__ Whh,
                                                     const float* __restrict__ bih,
                                                     const float* __restrict__ bhh,
                                                     unsigned short* __restrict__ WL1,
                                                     unsigned short* __restrict__ WL2,
                                                     unsigned short* __restrict__ Wt,
                                                     float* __restrict__ bc){
    int idx = blockIdx.x*256 + threadIdx.x;
    if (idx < 24576){
        int g = idx >> 13, rem = idx & 8191, col = rem >> 7, k = rem & 127;
        float v = (k < 64) ? W1l[((size_t)g*64 + k)*64 + col]
                           : W1r[((size_t)g*64 + (k-64))*64 + col];
        WL1[idx] = f2bf(v);
    } else if (idx < 49152){
        int t = idx - 24576;
        int g = t >> 13, rem = t & 8191, col = rem >> 7, k = rem & 127;
        float v = (k < 64) ? W2l[((size_t)g*64 + k)*64 + col]
                           : W2r[((size_t)g*64 + (k-64))*64 + col];
        WL2[t] = f2bf(v);
    } else if (idx < 81920){
        int t = idx - 49152;
        int col = t >> 7, k = t & 127;
        float v = (k < 64) ? Wih[col*64 + k] : Whh[col*64 + (k - 64)];
        Wt[t] = f2bf(v);
    } else if (idx < 82176){
        int t = idx - 81920;
        bc[t] = bih[t] + bhh[t];
    }
}

// ---------------- SAGE layer: barrier-free, per-wave slices; dual-row gather with
// explicit load/consume separation (16 loads in flight); XCD-affinity swizzle ----------------

#define WP 72

__global__ __launch_bounds__(256) void layer_kernel(const unsigned short* __restrict__ xb,
                                                    const int* __restrict__ off2,
                                                    const int* __restrict__ deg2,
                                                    const int* __restrict__ csr,
                                                    const unsigned short* __restrict__ WL,
                                                    const float* __restrict__ bias,
                                                    unsigned short* __restrict__ outb){
    __shared__ unsigned short sM[4][16*WP];  // mean slices
    __shared__ unsigned short sO[4][16*WP];  // out slices
    // XCD-affinity swizzle: dispatch round-robins blocks over 8 XCDs (L%8).
    int L = blockIdx.x;
    int xcd = L & 7, k = L >> 3;
    int task = xcd*LPERX + k;
    int sg = task / LTILES;
    int tile = task - sg*LTILES;
    if (tile >= (NN + 63)/64) return;   // pad task (no barriers in kernel -> safe)
    int g = sg % G;
    int tid = threadIdx.x;
    int row0 = tile*64;
    const unsigned short* inb = xb + (size_t)sg*NN*D;

    int wave = tid >> 6, lane = tid & 63;
    int i0 = row0 + wave*16;

    // aggregation: 8 groups x 8 lanes; group owns rows (gp, 8+gp) jointly
    {
        int gp = lane >> 3, fl = lane & 7;
        int ii = min(i0 + (lane & 15), NN-1);
        int val = (lane < 16) ? off2[sg*NN + ii] : ((lane < 32) ? deg2[sg*NN + ii] : 0);
        int r0loc = gp, r1loc = 8 + gp;
        int a0  = __shfl(val, r0loc, 64);
        int dg0 = __shfl(val, 16 + r0loc, 64);
        int a1  = __shfl(val, r1loc, 64);
        int dg1 = __shfl(val, 16 + r1loc, 64);
        if (i0 + r0loc >= NN) dg0 = 0;
        if (i0 + r1loc >= NN) dg1 = 0;
        float acc0[8] = {0,0,0,0,0,0,0,0};
        float acc1[8] = {0,0,0,0,0,0,0,0};
        int mx = max(dg0, dg1);
        for (int base = 0; base < mx; base += 8){
            int my0 = 0, my1 = 0;
            if (base + fl < dg0) my0 = csr[a0 + base + fl];
            if (base + fl < dg1) my1 = csr[a1 + base + fl];
            // phase 1: issue all 16 gathers into named regs (keeps them in flight)
            uint4 v0[8], v1[8];
            #pragma unroll
            for (int j = 0; j < 8; ++j){
                int n0j = __shfl(my0, gp*8 + j, 64);
                int n1j = __shfl(my1, gp*8 + j, 64);
                v0[j] = (uint4){0,0,0,0};
                v1[j] = (uint4){0,0,0,0};
                if (base + j < dg0) v0[j] = *(const uint4*)&inb[(size_t)n0j*D + fl*8];
                if (base + j < dg1) v1[j] = *(const uint4*)&inb[(size_t)n1j*D + fl*8];
            }
            // phase 2: unpack + accumulate
            #pragma unroll
            for (int j = 0; j < 8; ++j){
                acc0[0] += __uint_as_float(v0[j].x << 16);
                acc0[1] += __uint_as_float(v0[j].x & 0xFFFF0000u);
                acc0[2] += __uint_as_float(v0[j].y << 16);
                acc0[3] += __uint_as_float(v0[j].y & 0xFFFF0000u);
                acc0[4] += __uint_as_float(v0[j].z << 16);
                acc0[5] += __uint_as_float(v0[j].z & 0xFFFF0000u);
                acc0[6] += __uint_as_float(v0[j].w << 16);
                acc0[7] += __uint_as_float(v0[j].w & 0xFFFF0000u);
                acc1[0] += __uint_as_float(v1[j].x << 16);
                acc1[1] += __uint_as_float(v1[j].x & 0xFFFF0000u);
                acc1[2] += __uint_as_float(v1[j].y << 16);
                acc1[3] += __uint_as_float(v1[j].y & 0xFFFF0000u);
                acc1[4] += __uint_as_float(v1[j].z << 16);
                acc1[5] += __uint_as_float(v1[j].z & 0xFFFF0000u);
                acc1[6] += __uint_as_float(v1[j].w << 16);
                acc1[7] += __uint_as_float(v1[j].w & 0xFFFF0000u);
            }
        }
        float inv0 = (dg0 > 0) ? rcpf((float)dg0) : 0.0f;
        float inv1 = (dg1 > 0) ? rcpf((float)dg1) : 0.0f;
        uint4 pk;
        pk.x = (unsigned)f2bf(acc0[0]*inv0) | ((unsigned)f2bf(acc0[1]*inv0) << 16);
        pk.y = (unsigned)f2bf(acc0[2]*inv0) | ((unsigned)f2bf(acc0[3]*inv0) << 16);
        pk.z = (unsigned)f2bf(acc0[4]*inv0) | ((unsigned)f2bf(acc0[5]*inv0) << 16);
        pk.w = (unsigned)f2bf(acc0[6]*inv0) | ((unsigned)f2bf(acc0[7]*inv0) << 16);
        *(uint4*)&sM[wave][r0loc*WP + fl*8] = pk;
        pk.x = (unsigned)f2bf(acc1[0]*inv1) | ((unsigned)f2bf(acc1[1]*inv1) << 16);
        pk.y = (unsigned)f2bf(acc1[2]*inv1) | ((unsigned)f2bf(acc1[3]*inv1) << 16);
        pk.z = (unsigned)f2bf(acc1[4]*inv1) | ((unsigned)f2bf(acc1[5]*inv1) << 16);
        pk.w = (unsigned)f2bf(acc1[6]*inv1) | ((unsigned)f2bf(acc1[7]*inv1) << 16);
        *(uint4*)&sM[wave][r1loc*WP + fl*8] = pk;
    }
    // no barrier: consumers are this same wave (lgkmcnt ordering)

    int n0 = lane & 15, q = lane >> 4;
    const unsigned short* WLg = WL + (size_t)g*64*128;
    f32x4 accv[4];
    #pragma unroll
    for (int ct = 0; ct < 4; ++ct) accv[ct] = (f32x4){0.f,0.f,0.f,0.f};
    int irow = min(i0 + n0, NN-1);
    #pragma unroll
    for (int kc = 0; kc < 4; ++kc){
        bf16x8 af;
        if (kc < 2) af = *(const bf16x8*)&sM[wave][n0*WP + kc*32 + q*8];
        else        af = *(const bf16x8*)&inb[(size_t)irow*D + (kc-2)*32 + q*8];
        #pragma unroll
        for (int ct = 0; ct < 4; ++ct){
            bf16x8 bfr = *(const bf16x8*)&WLg[(ct*16 + n0)*128 + kc*32 + q*8];
            accv[ct] = __builtin_amdgcn_mfma_f32_16x16x32_bf16(af, bfr, accv[ct], 0, 0, 0);
        }
    }
    #pragma unroll
    for (int ct = 0; ct < 4; ++ct){
        float bv = bias[g*64 + ct*16 + n0];
        #pragma unroll
        for (int reg = 0; reg < 4; ++reg)
            sO[wave][(q*4+reg)*WP + ct*16 + n0] = f2bf(tanhf_fast(accv[ct][reg] + bv));
    }
    #pragma unroll
    for (int pass = 0; pass < 2; ++pass){
        int rloc = pass*8 + (lane >> 3), chunk = lane & 7;
        int i = i0 + rloc;
        if (i < NN){
            uint4 v = *(const uint4*)&sO[wave][rloc*WP + chunk*8];
            *(uint4*)&outb[((size_t)sg*NN + i)*D + chunk*8] = v;
        }
    }
}

// ---------------- LSTM: col-partitioned waves; Wt read once per block; 3 barriers ----------------

__global__ __launch_bounds__(256) void lstm_kernel(const unsigned short* __restrict__ h2b,
                                                   const unsigned short* __restrict__ Wt,
                                                   const float* __restrict__ bc,
                                                   float* __restrict__ out){
    __shared__ unsigned short sH[64*WP];  // 9.2 KB, whole block's h
    int tid = threadIdx.x;
    int b0 = blockIdx.x * 64;
    int wave = tid >> 6, lane = tid & 63;
    int n0 = lane & 15, q = lane >> 4;
    int jcol = wave*16 + n0;              // output col j in [0,64)

    float bb[4];
    #pragma unroll
    for (int T = 0; T < 4; ++T) bb[T] = bc[T*64 + jcol];

    float c[4][4];  // [rt][reg]
    #pragma unroll
    for (int rt = 0; rt < 4; ++rt)
        #pragma unroll
        for (int reg = 0; reg < 4; ++reg) c[rt][reg] = 0.0f;

    int s_[4], n_[4];
    #pragma unroll
    for (int rt = 0; rt < 4; ++rt){
        int b = b0 + rt*16 + n0;
        s_[rt] = b / NN; n_[rt] = b - s_[rt]*NN;
    }

    #pragma unroll
    for (int t = 0; t < G; ++t){
        f32x4 accv[4][4];  // [rt][T]
        #pragma unroll
        for (int rt = 0; rt < 4; ++rt)
            #pragma unroll
            for (int T = 0; T < 4; ++T) accv[rt][T] = (f32x4){0.f,0.f,0.f,0.f};

        int nkc = (t == 0) ? 2 : 4;
        #pragma unroll
        for (int kc = 0; kc < 4; ++kc){
            if (kc >= nkc) break;
            bf16x8 af[4];
            #pragma unroll
            for (int rt = 0; rt < 4; ++rt){
                if (kc < 2) af[rt] = *(const bf16x8*)&h2b[((size_t)(s_[rt]*G + t)*NN + n_[rt])*D + kc*32 + q*8];
                else        af[rt] = *(const bf16x8*)&sH[(rt*16 + n0)*WP + (kc-2)*32 + q*8];
            }
            #pragma unroll
            for (int T = 0; T < 4; ++T){
                int ct = T*4 + wave;
                bf16x8 bfr = *(const bf16x8*)&Wt[(ct*16 + n0)*128 + kc*32 + q*8];
                #pragma unroll
                for (int rt = 0; rt < 4; ++rt)
                    accv[rt][T] = __builtin_amdgcn_mfma_f32_16x16x32_bf16(af[rt], bfr, accv[rt][T], 0, 0, 0);
            }
        }
        if (t > 0) __syncthreads();   // WAR: all sH reads done before overwrite

        #pragma unroll
        for (int rt = 0; rt < 4; ++rt){
            #pragma unroll
            for (int reg = 0; reg < 4; ++reg){
                float ig = sigmf(accv[rt][0][reg] + bb[0]);
                float fg = sigmf(accv[rt][1][reg] + bb[1]);
                float gg = tanhf_fast(accv[rt][2][reg] + bb[2]);
                float og = sigmf(accv[rt][3][reg] + bb[3]);
                float cn = fg*c[rt][reg] + ig*gg;
                c[rt][reg] = cn;
                float hv = og * tanhf_fast(cn);
                int row = rt*16 + q*4 + reg;
                if (t < G-1) sH[row*WP + jcol] = f2bf(hv);
                else         out[(size_t)(b0 + row)*D + jcol] = hv;
            }
        }
        if (t < G-1) __syncthreads(); // RAW: h visible before next t's reads
    }
}

// ---------------- host ----------------

extern "C" void kernel_launch(void* const* d_in, const int* in_sizes, int n_in,
                              void* d_out, int out_size, void* d_ws, size_t ws_size,
                              hipStream_t stream) {
    const float* x   = (const float*)d_in[0];
    const int*   ei  = (const int*)  d_in[1];
    const float* W1l = (const float*)d_in[2];
    const float* W1r = (const float*)d_in[3];
    const float* b1  = (const float*)d_in[4];
    const float* W2l = (const float*)d_in[5];
    const float* W2r = (const float*)d_in[6];
    const float* b2  = (const float*)d_in[7];
    const float* Wih = (const float*)d_in[8];
    const float* Whh = (const float*)d_in[9];
    const float* bih = (const float*)d_in[10];
    const float* bhh = (const float*)d_in[11];
    float* out = (float*)d_out;

    char* ws = (char*)d_ws;
    size_t cur = 0;
    auto alloc = [&](size_t bytes)->void*{
        cur = (cur + 255) & ~(size_t)255;
        void* p = ws + cur; cur += bytes; return p;
    };
    int*   bkt  = (int*)alloc((size_t)SG*RGS*BCAP*4);   // buckets, then CSR in place
    int*   bcur = (int*)alloc((size_t)SG*RGS*4);
    int*   off2 = (int*)alloc((size_t)SG*NN*4);
    int*   deg2 = (int*)alloc((size_t)SG*NN*4);
    unsigned short* xb  = (unsigned short*)alloc((size_t)SG*NN*D*2);
    unsigned short* h1b = (unsigned short*)alloc((size_t)SG*NN*D*2);
    unsigned short* h2b = (unsigned short*)alloc((size_t)SG*NN*D*2);
    unsigned short* WL1 = (unsigned short*)alloc((size_t)G*64*128*2);
    unsigned short* WL2 = (unsigned short*)alloc((size_t)G*64*128*2);
    unsigned short* Wt  = (unsigned short*)alloc((size_t)256*128*2);
    float* bc   = (float*)alloc((size_t)256*4);
    (void)ws_size; (void)in_sizes; (void)n_in; (void)out_size;

    (void)hipMemsetAsync(bcur, 0, (size_t)SG*RGS*4, stream);

    convert_kernel<<<(SG*NN*16 + 255)/256, 256, 0, stream>>>(x, xb);
    binA_kernel  <<<dim3(CHUNKA, SG), 256, 0, stream>>>(ei, bcur, bkt);
    buildB_kernel<<<SG*RGS, 256, 0, stream>>>(bkt, bcur, off2, deg2);
    wprep2_kernel<<<321, 256, 0, stream>>>(W1l, W1r, W2l, W2r, Wih, Whh, bih, bhh,
                                           WL1, WL2, Wt, bc);

    layer_kernel<<<LTASKS, 256, 0, stream>>>(xb,  off2, deg2, bkt, WL1, b1, h1b);
    layer_kernel<<<LTASKS, 256, 0, stream>>>(h1b, off2, deg2, bkt, WL2, b2, h2b);

    lstm_kernel <<<(S*NN)/64, 256, 0, stream>>>(h2b, Wt, bc, out);
}